// Round 9
// baseline (478.911 us; speedup 1.0000x reference)
//
#include <hip/hip_runtime.h>
#include <math.h>

// ---------------------------------------------------------------------------
// SimpleVQAutoEncoder forward.
// conv1 -> h1 as split-bf16 hi/lo, layout [n][y][x][cin] (coalesced).
// conv2: split-bf16 MFMA GEMM over (tap,cin) K=144, in-register maxpool.
// VQ: split-bf16 MFMA distances; codebook pre-split (k_prep) into global
//   cbh/cbl/c2 and B-frags read straight from L2 (no LDS, no per-block
//   conversion); near-tie flagging + fp64 repair => indices == numpy fp64.
// Decoder: parity-collapsed 2x2 convs.
// Outputs d_out (fp32): recon 4194304 | indices 262144 | loss 1
// ---------------------------------------------------------------------------

#define GELUF(v) (0.5f * (v) * (1.0f + erff((v) * 0.70710678118654752440f)))
#define MAXFLAG 262144

typedef __attribute__((ext_vector_type(8))) short short8;
typedef __attribute__((ext_vector_type(4))) float float4v;

static __device__ inline unsigned short f2bf(float f) {
    unsigned u = __float_as_uint(f);
    unsigned r = (u + 0x7FFFu + ((u >> 16) & 1u)) >> 16;
    return (unsigned short)r;
}
static __device__ inline float bf2f(unsigned short h) {
    return __uint_as_float(((unsigned)h) << 16);
}

// conv1 (1->16) + maxpool2 + gelu; output split-bf16 hi/lo [n][y][x][cin].
__global__ __launch_bounds__(256) void k_conv1b(const float* __restrict__ x,
                                                const float* __restrict__ w1,
                                                const float* __restrict__ b1,
                                                unsigned short* __restrict__ h1h,
                                                unsigned short* __restrict__ h1l) {
    int idx = blockIdx.x * 256 + threadIdx.x;
    int xo = idx & 127;
    int yo = (idx >> 7) & 127;
    int n  = idx >> 14;
    const float* xin = x + (size_t)n * 65536;

    float patch[4][4];
    int y0 = 2 * yo - 1, x0 = 2 * xo - 1;
#pragma unroll
    for (int i = 0; i < 4; i++) {
        int iy = y0 + i;
        bool oy = (iy >= 0 && iy < 256);
#pragma unroll
        for (int j = 0; j < 4; j++) {
            int ix = x0 + j;
            patch[i][j] = (oy && ix >= 0 && ix < 256) ? xin[iy * 256 + ix] : 0.0f;
        }
    }
    unsigned short hi[16], lo[16];
#pragma unroll
    for (int c = 0; c < 16; c++) {
        float m = -INFINITY;
#pragma unroll
        for (int sy = 0; sy < 2; sy++)
#pragma unroll
            for (int sx = 0; sx < 2; sx++) {
                float acc = b1[c];
#pragma unroll
                for (int ky = 0; ky < 3; ky++)
#pragma unroll
                    for (int kx = 0; kx < 3; kx++)
                        acc += w1[c * 9 + ky * 3 + kx] * patch[sy + ky][sx + kx];
                m = fmaxf(m, acc);
            }
        float g = GELUF(m);
        hi[c] = f2bf(g);
        lo[c] = f2bf(g - bf2f(hi[c]));
    }
    size_t off = ((size_t)idx) << 4;
    uint ph[8], pl[8];
#pragma unroll
    for (int c2 = 0; c2 < 8; c2++) {
        ph[c2] = (uint)hi[2 * c2] | ((uint)hi[2 * c2 + 1] << 16);
        pl[c2] = (uint)lo[2 * c2] | ((uint)lo[2 * c2 + 1] << 16);
    }
    uint4* dh = (uint4*)(h1h + off);
    uint4* dl = (uint4*)(h1l + off);
    dh[0] = make_uint4(ph[0], ph[1], ph[2], ph[3]);
    dh[1] = make_uint4(ph[4], ph[5], ph[6], ph[7]);
    dl[0] = make_uint4(pl[0], pl[1], pl[2], pl[3]);
    dl[1] = make_uint4(pl[4], pl[5], pl[6], pl[7]);
}

// conv2 (16->32) + maxpool2 via split-bf16 MFMA (unchanged).
__global__ __launch_bounds__(256) void k_conv2m(const unsigned short* __restrict__ h1h,
                                                const unsigned short* __restrict__ h1l,
                                                const unsigned short* __restrict__ w2h,
                                                const unsigned short* __restrict__ w2l,
                                                const float* __restrict__ b2,
                                                float* __restrict__ h2) {
    __shared__ unsigned short s_hi[18 * 2 * 18 * 8];
    __shared__ unsigned short s_lo[18 * 2 * 18 * 8];
    __shared__ unsigned short s_wh[32 * 10 * 2 * 8];
    __shared__ unsigned short s_wl[32 * 10 * 2 * 8];
    __shared__ float s_pool[32 * 64];

    int tid = threadIdx.x;
    int n = blockIdx.x >> 6;
    int tile = blockIdx.x & 63;
    int cx0 = (tile & 7) << 4, cy0 = (tile >> 3) << 4;

    {
        const uint* gh = (const uint*)w2h;
        const uint* gl = (const uint*)w2l;
        uint* dh = (uint*)s_wh; uint* dl = (uint*)s_wl;
        for (int e = tid; e < 2560; e += 256) { dh[e] = gh[e]; dl[e] = gl[e]; }
    }
    {
        const uint* gh = (const uint*)(h1h + (((size_t)n) << 18));
        const uint* gl = (const uint*)(h1l + (((size_t)n) << 18));
        uint* dh = (uint*)s_hi; uint* dl = (uint*)s_lo;
        for (int e = tid; e < 2592; e += 256) {
            int r = e / 144;
            int rem = e - r * 144;
            int c = rem >> 3;
            int dw = rem & 7;
            int y = cy0 - 1 + r, xx = cx0 - 1 + c;
            uint vh = 0, vl = 0;
            if (y >= 0 && y < 128 && xx >= 0 && xx < 128) {
                size_t g = ((size_t)((y << 7) + xx) << 3) + dw;
                vh = gh[g]; vl = gl[g];
            }
            int half = dw >> 2;
            int du = (((r * 2 + half) * 18 + c) << 2) + (dw & 3);
            dh[du] = vh; dl[du] = vl;
        }
    }
    __syncthreads();

    int lane = tid & 63, wid = tid >> 6;
    int m = lane & 15, quad = lane >> 4;
    int tl = quad >> 1, half = quad & 1;

    float4v acc[4][2];
#pragma unroll
    for (int mt = 0; mt < 4; mt++)
#pragma unroll
        for (int nt = 0; nt < 2; nt++)
            acc[mt][nt] = (float4v){0.0f, 0.0f, 0.0f, 0.0f};

    for (int s = 0; s < 5; s++) {
        int tA = (s < 4) ? (2 * s + tl) : 8;
        int tB = (s < 4) ? (2 * s + tl) : (8 + tl);
        short8 Bh[2], Bl[2];
#pragma unroll
        for (int nt = 0; nt < 2; nt++) {
            int u = ((nt * 16 + m) * 10 + tB) * 2 + half;
            Bh[nt] = *(const short8*)(s_wh + (u << 3));
            Bl[nt] = *(const short8*)(s_wl + (u << 3));
        }
        int ky = tA / 3, kx = tA - 3 * (tA / 3);
        short8 Ah[4], Al[4];
#pragma unroll
        for (int mt = 0; mt < 4; mt++) {
            int u = (((wid * 4 + mt + ky) * 2 + half) * 18) + m + kx;
            Ah[mt] = *(const short8*)(s_hi + (u << 3));
            Al[mt] = *(const short8*)(s_lo + (u << 3));
        }
#pragma unroll
        for (int mt = 0; mt < 4; mt++)
#pragma unroll
            for (int nt = 0; nt < 2; nt++) {
                float4v z = acc[mt][nt];
                z = __builtin_amdgcn_mfma_f32_16x16x32_bf16(Al[mt], Bh[nt], z, 0, 0, 0);
                z = __builtin_amdgcn_mfma_f32_16x16x32_bf16(Ah[mt], Bl[nt], z, 0, 0, 0);
                z = __builtin_amdgcn_mfma_f32_16x16x32_bf16(Ah[mt], Bh[nt], z, 0, 0, 0);
                acc[mt][nt] = z;
            }
    }

#pragma unroll
    for (int nt = 0; nt < 2; nt++) {
        int cout = nt * 16 + m;
        float bias = b2[cout];
#pragma unroll
        for (int mtp = 0; mtp < 2; mtp++) {
            float4v a0 = acc[2 * mtp][nt], a1 = acc[2 * mtp + 1][nt];
            float p0 = fmaxf(fmaxf(a0[0], a0[1]), fmaxf(a1[0], a1[1])) + bias;
            float p1 = fmaxf(fmaxf(a0[2], a0[3]), fmaxf(a1[2], a1[3])) + bias;
            int py = wid * 2 + mtp;
            int px = quad * 2;
            s_pool[cout * 64 + py * 8 + px]     = p0;
            s_pool[cout * 64 + py * 8 + px + 1] = p1;
        }
    }
    __syncthreads();
    {
        int c = tid >> 3, pr = tid & 7;
        float* dst = h2 + (((size_t)(n * 32 + c)) << 12) + ((cy0 >> 1) + pr) * 64 + (cx0 >> 1);
        const float4* src = (const float4*)(s_pool + c * 64 + pr * 8);
        ((float4*)dst)[0] = src[0];
        ((float4*)dst)[1] = src[1];
    }
}

// VQ via split-bf16 MFMA; B-frags straight from global (L2-resident codebook,
// pre-split by k_prep). No codebook LDS, no conversion, x2 hoisted out of the
// select loop (argmin over c2 - 2*dot; x2 added back after lane reduction).
__global__ __launch_bounds__(256) void k_vq_mfma(const float* __restrict__ h2,
                                                 const unsigned short* __restrict__ cbh,
                                                 const unsigned short* __restrict__ cbl,
                                                 const float* __restrict__ c2g,
                                                 const float* __restrict__ cb,
                                                 float* __restrict__ q,
                                                 float* __restrict__ idx_out,
                                                 float* __restrict__ loss_out,
                                                 int* __restrict__ nflag,
                                                 int* __restrict__ flags) {
    __shared__ float s_best[256], s_best2[256];
    __shared__ int   s_bi[256];
    __shared__ float wsum[4];

    int tid = threadIdx.x;
    int lane = tid & 63;
    int wid  = tid >> 6;
    int m    = lane & 15;
    int quad = lane >> 4;

    int img = blockIdx.x >> 4;
    int sp0 = (blockIdx.x & 15) << 8;
    const float* xb = h2 + ((size_t)(img * 32) << 12) + sp0;

    // A fragments + per-row x2
    short8 Ahi[4], Alo[4];
    float x2r[4][4];
    float x2own[4];
#pragma unroll
    for (int mt = 0; mt < 4; mt++) {
        const float* xp = xb + wid * 64 + mt * 16 + m;
        float x2 = 0.0f;
#pragma unroll
        for (int j = 0; j < 8; j++) {
            float fe = xp[(size_t)(quad * 8 + j) << 12];
            x2 += fe * fe;
            unsigned short hi = f2bf(fe);
            unsigned short lo = f2bf(fe - bf2f(hi));
            Ahi[mt][j] = (short)hi;
            Alo[mt][j] = (short)lo;
        }
        x2 += __shfl_xor(x2, 16);
        x2 += __shfl_xor(x2, 32);
        x2own[mt] = x2;
    }
#pragma unroll
    for (int mt = 0; mt < 4; mt++)
#pragma unroll
        for (int r = 0; r < 4; r++)
            x2r[mt][r] = __shfl(x2own[mt], quad * 4 + r);

    float best[4][4], best2[4][4];
    int bi[4][4];
#pragma unroll
    for (int mt = 0; mt < 4; mt++)
#pragma unroll
        for (int r = 0; r < 4; r++) {
            best[mt][r] = INFINITY; best2[mt][r] = INFINITY; bi[mt][r] = 0;
        }

    // software-pipelined B loads (one nt ahead), straight from global
    size_t boff = ((size_t)m << 5) + (quad << 3);  // code m, k-chunk quad
    short8 Bh = *(const short8*)(cbh + boff);
    short8 Bl = *(const short8*)(cbl + boff);
    float  c2v = c2g[m];

    for (int nt = 0; nt < 32; nt++) {
        short8 curBh = Bh, curBl = Bl;
        float  curc2 = c2v;
        if (nt < 31) {
            size_t o = boff + ((size_t)(nt + 1) << 9);  // +16 codes * 32
            Bh = *(const short8*)(cbh + o);
            Bl = *(const short8*)(cbl + o);
            c2v = c2g[(nt + 1) * 16 + m];
        }
        int ncode = nt * 16 + m;

        float4v acc[4];
#pragma unroll
        for (int mt = 0; mt < 4; mt++) {
            float4v z = {0.0f, 0.0f, 0.0f, 0.0f};
            z = __builtin_amdgcn_mfma_f32_16x16x32_bf16(Alo[mt], curBh, z, 0, 0, 0);
            z = __builtin_amdgcn_mfma_f32_16x16x32_bf16(Ahi[mt], curBl, z, 0, 0, 0);
            z = __builtin_amdgcn_mfma_f32_16x16x32_bf16(Ahi[mt], curBh, z, 0, 0, 0);
            acc[mt] = z;
        }
#pragma unroll
        for (int mt = 0; mt < 4; mt++)
#pragma unroll
            for (int r = 0; r < 4; r++) {
                float dist = fmaf(acc[mt][r], -2.0f, curc2);  // rel: true dist - x2
                best2[mt][r] = fminf(best2[mt][r], fmaxf(dist, best[mt][r]));
                bool lt = dist < best[mt][r];
                bi[mt][r] = lt ? ncode : bi[mt][r];
                best[mt][r] = fminf(best[mt][r], dist);
            }
    }

    // reduce across the 16 column-lanes of each quad; add x2 back at the end
#pragma unroll
    for (int mt = 0; mt < 4; mt++)
#pragma unroll
        for (int r = 0; r < 4; r++) {
            float b1v = best[mt][r], b2v = best2[mt][r];
            int   biv = bi[mt][r];
#pragma unroll
            for (int mask = 1; mask < 16; mask <<= 1) {
                float ob = __shfl_xor(b1v, mask);
                float ob2 = __shfl_xor(b2v, mask);
                int   obi = __shfl_xor(biv, mask);
                b2v = fminf(fminf(b2v, ob2), fmaxf(b1v, ob));
                if (ob < b1v || (ob == b1v && obi < biv)) { b1v = ob; biv = obi; }
            }
            if (m == 0) {
                int p = wid * 64 + mt * 16 + quad * 4 + r;
                s_best[p] = b1v + x2r[mt][r];
                s_best2[p] = b2v + x2r[mt][r];
                s_bi[p] = biv;
            }
        }
    __syncthreads();

    int pos = blockIdx.x * 256 + tid;
    float bb = s_best[tid], bb2 = s_best2[tid];
    int   kk = s_bi[tid];
    idx_out[pos] = (float)kk;

    // eps ~10x the worst-case split-bf16 distance error (~2e-3)
    float eps = 0.02f + 0.0005f * fabsf(bb);
    if (bb2 - bb < eps) {
        int slot = atomicAdd(nflag, 1);
        if (slot < MAXFLAG) flags[slot] = pos;
    }

    const float4* crow = (const float4*)(cb + kk * 32);
    float* qp = q + ((size_t)(img * 32) << 12) + sp0 + tid;
#pragma unroll
    for (int j = 0; j < 8; j++) {
        float4 f4 = crow[j];
        qp[(size_t)(j * 4 + 0) << 12] = f4.x;
        qp[(size_t)(j * 4 + 1) << 12] = f4.y;
        qp[(size_t)(j * 4 + 2) << 12] = f4.z;
        qp[(size_t)(j * 4 + 3) << 12] = f4.w;
    }

    float lsum = fmaxf(bb, 0.0f);
#pragma unroll
    for (int o = 32; o > 0; o >>= 1) lsum += __shfl_down(lsum, o);
    if (lane == 0) wsum[wid] = lsum;
    __syncthreads();
    if (tid == 0)
        atomicAdd(loss_out, (wsum[0] + wsum[1] + wsum[2] + wsum[3]) * (1.0f / 8388608.0f));
}

// fp64 repair: one wave per flagged position (unchanged).
__global__ __launch_bounds__(64) void k_repair(const float* __restrict__ x,
                                               const float* __restrict__ w1,
                                               const float* __restrict__ b1,
                                               const float* __restrict__ w2,
                                               const float* __restrict__ b2,
                                               const float* __restrict__ cb,
                                               float* __restrict__ q,
                                               float* __restrict__ idx_out,
                                               const int* __restrict__ nflag,
                                               const int* __restrict__ flags) {
    __shared__ double h1w[16][16];
    __shared__ double xvd[32];
    int lane = threadIdx.x;
    int cnt = *nflag;
    if (cnt > MAXFLAG) cnt = MAXFLAG;

    for (int fi = blockIdx.x; fi < cnt; fi += gridDim.x) {
        int pos = flags[fi];
        int n = pos >> 12, sp = pos & 4095, yo = sp >> 6, xo = sp & 63;

        int pix = lane >> 2, cg = lane & 3;
        int dy = pix >> 2, dx = pix & 3;
        int yh = 2 * yo - 1 + dy, xh = 2 * xo - 1 + dx;
        double hv[4] = {0.0, 0.0, 0.0, 0.0};
        if (yh >= 0 && yh < 128 && xh >= 0 && xh < 128) {
            const float* xin = x + (size_t)n * 65536;
            double patch[4][4];
            int y0 = 2 * yh - 1, x0 = 2 * xh - 1;
#pragma unroll
            for (int i = 0; i < 4; i++) {
                int iy = y0 + i;
                bool oy = (iy >= 0 && iy < 256);
#pragma unroll
                for (int j = 0; j < 4; j++) {
                    int ix = x0 + j;
                    patch[i][j] = (oy && ix >= 0 && ix < 256) ? (double)xin[iy * 256 + ix] : 0.0;
                }
            }
#pragma unroll
            for (int j = 0; j < 4; j++) {
                int c = cg * 4 + j;
                double mm = -INFINITY;
#pragma unroll
                for (int sy = 0; sy < 2; sy++)
#pragma unroll
                    for (int sx = 0; sx < 2; sx++) {
                        double acc = (double)b1[c];
#pragma unroll
                        for (int ky = 0; ky < 3; ky++)
#pragma unroll
                            for (int kx = 0; kx < 3; kx++)
                                acc += (double)w1[c * 9 + ky * 3 + kx] * patch[sy + ky][sx + kx];
                        mm = fmax(mm, acc);
                    }
                hv[j] = 0.5 * mm * (1.0 + erf(mm * 0.70710678118654752440));
            }
        }
        __syncthreads();
#pragma unroll
        for (int j = 0; j < 4; j++) h1w[cg * 4 + j][pix] = hv[j];
        __syncthreads();

        if (lane < 32) {
            double bb = (double)b2[lane];
            double acc[2][2] = {{bb, bb}, {bb, bb}};
            for (int cin = 0; cin < 16; cin++)
#pragma unroll
                for (int ky = 0; ky < 3; ky++)
#pragma unroll
                    for (int kx = 0; kx < 3; kx++) {
                        double wv = (double)w2[((lane * 16 + cin) * 3 + ky) * 3 + kx];
#pragma unroll
                        for (int sy = 0; sy < 2; sy++)
#pragma unroll
                            for (int sx = 0; sx < 2; sx++)
                                acc[sy][sx] += wv * h1w[cin][(sy + ky) * 4 + (sx + kx)];
                    }
            xvd[lane] = fmax(fmax(acc[0][0], acc[0][1]), fmax(acc[1][0], acc[1][1]));
        }
        __syncthreads();

        double x2 = 0.0;
        for (int d = 0; d < 32; d++) x2 += xvd[d] * xvd[d];
        double best = INFINITY;
        int bi = 0;
        for (int j = 0; j < 8; j++) {
            int k = lane * 8 + j;
            const float* cp = cb + k * 32;
            double c2 = 0.0, dot = 0.0;
#pragma unroll
            for (int d = 0; d < 32; d++) {
                double cd = (double)cp[d];
                c2 += cd * cd;
                dot += xvd[d] * cd;
            }
            double dist = x2 - 2.0 * dot + c2;
            if (dist < best) { best = dist; bi = k; }
        }
#pragma unroll
        for (int o = 32; o > 0; o >>= 1) {
            double od = __shfl_down(best, o);
            int oi = __shfl_down(bi, o);
            if (od < best || (od == best && oi < bi)) { best = od; bi = oi; }
        }
        bi = __shfl(bi, 0);

        if (lane == 0) idx_out[(size_t)n * 4096 + sp] = (float)bi;
        if (lane < 32) q[((size_t)(n * 32 + lane) << 12) + sp] = cb[bi * 32 + lane];
    }
}

// prep: parity decoder weights + split-bf16 conv2 weights + split codebook.
__global__ __launch_bounds__(256) void k_prep(const float* __restrict__ w2,
                                              const float* __restrict__ w3,
                                              const float* __restrict__ w4,
                                              const float* __restrict__ cb,
                                              unsigned short* __restrict__ w2h,
                                              unsigned short* __restrict__ w2l,
                                              float* __restrict__ wc3,
                                              float* __restrict__ wc4,
                                              unsigned short* __restrict__ cbh,
                                              unsigned short* __restrict__ cbl,
                                              float* __restrict__ c2g) {
    const int masks[2][2] = {{1, 6}, {3, 4}};
    for (int e = threadIdx.x; e < 8192; e += 256) {
        int cout = e & 15, tap = (e >> 4) & 3, cin = (e >> 6) & 31, pp = e >> 11;
        int rm = masks[pp >> 1][tap >> 1], cm = masks[pp & 1][tap & 1];
        float s = 0.0f;
        for (int ky = 0; ky < 3; ky++)
            if ((rm >> ky) & 1)
                for (int kx = 0; kx < 3; kx++)
                    if ((cm >> kx) & 1) s += w3[(cout * 32 + cin) * 9 + ky * 3 + kx];
        wc3[e] = s;
    }
    for (int e = threadIdx.x; e < 1024; e += 256) {
        int tap = e & 3, cin = (e >> 2) & 15, pp = e >> 6;
        int rm = masks[pp >> 1][tap >> 1], cm = masks[pp & 1][tap & 1];
        float s = 0.0f;
        for (int ky = 0; ky < 3; ky++)
            if ((rm >> ky) & 1)
                for (int kx = 0; kx < 3; kx++)
                    if ((cm >> kx) & 1) s += w4[cin * 9 + ky * 3 + kx];
        wc4[e] = s;
    }
    for (int e = threadIdx.x; e < 5120; e += 256) {
        int cout = e / 160;
        int rem = e - cout * 160;
        int tap = rem >> 4;
        int cin = rem & 15;
        float v = 0.0f;
        if (tap < 9) {
            int ky = tap / 3, kx = tap - 3 * (tap / 3);
            v = w2[((cout * 16 + cin) * 3 + ky) * 3 + kx];
        }
        unsigned short hi = f2bf(v);
        unsigned short lo = f2bf(v - bf2f(hi));
        w2h[e] = hi;
        w2l[e] = lo;
    }
    // codebook split: cbh/cbl [code][32] bf16, c2g fp32
    for (int e = threadIdx.x; e < 16384; e += 256) {
        float v = cb[e];
        unsigned short hi = f2bf(v);
        cbh[e] = hi;
        cbl[e] = f2bf(v - bf2f(hi));
    }
    for (int k = threadIdx.x; k < 512; k += 256) {
        float c2 = 0.0f;
#pragma unroll
        for (int d = 0; d < 32; d++) {
            float fe = cb[k * 32 + d];
            c2 += fe * fe;
        }
        c2g[k] = c2;
    }
}

// up2+conv3(32->16)+gelu, parity-collapsed (unchanged).
__global__ __launch_bounds__(256) void k_conv3n(const float* __restrict__ q,
                                                const float* __restrict__ wc3,
                                                const float* __restrict__ b3,
                                                float* __restrict__ h3) {
    int t = blockIdx.x * 256 + threadIdx.x;
    int b = t & 63, a = (t >> 6) & 63, n = t >> 12;

    float acc[2][2][16];
#pragma unroll
    for (int c = 0; c < 16; c++) {
        float bv = b3[c];
        acc[0][0][c] = bv; acc[0][1][c] = bv; acc[1][0][c] = bv; acc[1][1][c] = bv;
    }

    for (int cin = 0; cin < 32; cin++) {
        const float* qc = q + ((size_t)(n * 32 + cin) << 12);
        float v[3][3];
#pragma unroll
        for (int r = 0; r < 3; r++) {
            int qy = a - 1 + r;
            bool vy = (qy >= 0 && qy < 64);
#pragma unroll
            for (int cc = 0; cc < 3; cc++) {
                int qx = b - 1 + cc;
                v[r][cc] = (vy && qx >= 0 && qx < 64) ? qc[(qy << 6) + qx] : 0.0f;
            }
        }
        const float* wp = wc3 + cin * 64;
#pragma unroll
        for (int py = 0; py < 2; py++)
#pragma unroll
            for (int px = 0; px < 2; px++) {
                const float* wpp = wp + (py * 2 + px) * 2048;
#pragma unroll
                for (int dy = 0; dy < 2; dy++)
#pragma unroll
                    for (int dx = 0; dx < 2; dx++) {
                        float vv = v[py + dy][px + dx];
                        const float* wt = wpp + (dy * 2 + dx) * 16;
#pragma unroll
                        for (int c = 0; c < 16; c++)
                            acc[py][px][c] += wt[c] * vv;
                    }
            }
    }
#pragma unroll
    for (int c = 0; c < 16; c++)
#pragma unroll
        for (int py = 0; py < 2; py++) {
            float2 f2 = make_float2(GELUF(acc[py][0][c]), GELUF(acc[py][1][c]));
            *(float2*)(h3 + ((size_t)(n * 16 + c) << 14) + ((2 * a + py) << 7) + 2 * b) = f2;
        }
}

// up2+conv4(16->1)+clip, parity-collapsed (unchanged).
__global__ __launch_bounds__(256) void k_conv4n(const float* __restrict__ h3,
                                                const float* __restrict__ wc4,
                                                const float* __restrict__ b4,
                                                float* __restrict__ out) {
    int t = blockIdx.x * 256 + threadIdx.x;
    int b = t & 127, a = (t >> 7) & 127, n = t >> 14;

    float bv = b4[0];
    float acc[2][2] = {{bv, bv}, {bv, bv}};

    for (int cin = 0; cin < 16; cin++) {
        const float* hc = h3 + ((size_t)(n * 16 + cin) << 14);
        float v[3][3];
#pragma unroll
        for (int r = 0; r < 3; r++) {
            int hy = a - 1 + r;
            bool vy = (hy >= 0 && hy < 128);
#pragma unroll
            for (int cc = 0; cc < 3; cc++) {
                int hx = b - 1 + cc;
                v[r][cc] = (vy && hx >= 0 && hx < 128) ? hc[(hy << 7) + hx] : 0.0f;
            }
        }
#pragma unroll
        for (int py = 0; py < 2; py++)
#pragma unroll
            for (int px = 0; px < 2; px++)
#pragma unroll
                for (int dy = 0; dy < 2; dy++)
#pragma unroll
                    for (int dx = 0; dx < 2; dx++)
                        acc[py][px] += wc4[(py * 2 + px) * 64 + cin * 4 + dy * 2 + dx] *
                                       v[py + dy][px + dx];
    }
#pragma unroll
    for (int py = 0; py < 2; py++) {
        float2 f2 = make_float2(fminf(fmaxf(acc[py][0], -1.0f), 1.0f),
                                fminf(fmaxf(acc[py][1], -1.0f), 1.0f));
        *(float2*)(out + (size_t)n * 65536 + (2 * a + py) * 256 + 2 * b) = f2;
    }
}

extern "C" void kernel_launch(void* const* d_in, const int* in_sizes, int n_in,
                              void* d_out, int out_size, void* d_ws, size_t ws_size,
                              hipStream_t stream) {
    const float* x  = (const float*)d_in[0];
    const float* w1 = (const float*)d_in[1];
    const float* b1 = (const float*)d_in[2];
    const float* w2 = (const float*)d_in[3];
    const float* b2 = (const float*)d_in[4];
    const float* cb = (const float*)d_in[5];
    const float* w3 = (const float*)d_in[6];
    const float* b3 = (const float*)d_in[7];
    const float* w4 = (const float*)d_in[8];
    const float* b4 = (const float*)d_in[9];

    float* out      = (float*)d_out;
    float* idx_out  = out + 4194304;
    float* loss_out = out + 4194304 + 262144;

    char* ws = (char*)d_ws;
    unsigned short* h1h = (unsigned short*)ws;                      // [0,32M)
    unsigned short* h1l = (unsigned short*)(ws + (size_t)33554432); // [32M,64M)
    float* h2  = (float*)(ws + (size_t)67108864);                   // [64M,96M)
    float* h3  = (float*)ws;                                        // [0,64M) after conv2
    size_t T = 100663296;
    float* wc3 = (float*)(ws + T);                             // 32 KB
    float* wc4 = (float*)(ws + T + 32768);                     // 4 KB
    unsigned short* w2h = (unsigned short*)(ws + T + 36864);   // 10240 B
    unsigned short* w2l = (unsigned short*)(ws + T + 47104);   // 10240 B
    int* nflag = (int*)(ws + T + 57344);
    int* flags = (int*)(ws + T + 57408);                       // 1 MB
    size_t T2 = T + 57408 + 1048576;
    unsigned short* cbh = (unsigned short*)(ws + T2);          // 32 KB
    unsigned short* cbl = (unsigned short*)(ws + T2 + 32768);  // 32 KB
    float* c2g = (float*)(ws + T2 + 65536);                    // 2 KB

    (void)hipMemsetAsync(loss_out, 0, 4, stream);
    (void)hipMemsetAsync(nflag, 0, 4, stream);

    k_prep<<<1, 256, 0, stream>>>(w2, w3, w4, cb, w2h, w2l, wc3, wc4, cbh, cbl, c2g);
    k_conv1b<<<4096, 256, 0, stream>>>(x, w1, b1, h1h, h1l);
    k_conv2m<<<4096, 256, 0, stream>>>(h1h, h1l, w2h, w2l, b2, h2);
    k_vq_mfma<<<1024, 256, 0, stream>>>(h2, cbh, cbl, c2g, cb, h2, idx_out, loss_out, nflag, flags);
    k_repair<<<16384, 64, 0, stream>>>(x, w1, b1, w2, b2, cb, h2, idx_out, nflag, flags);
    k_conv3n<<<1024, 256, 0, stream>>>(h2, wc3, b3, h3);
    k_conv4n<<<4096, 256, 0, stream>>>(h3, wc4, b4, out);
}

// Round 10
// 462.680 us; speedup vs baseline: 1.0351x; 1.0351x over previous
//
#include <hip/hip_runtime.h>
#include <math.h>

// ---------------------------------------------------------------------------
// SimpleVQAutoEncoder forward.
// conv1 -> h1 split-bf16 hi/lo [n][y][x][cin]; conv2 split-bf16 MFMA GEMM.
// VQ: split-bf16 MFMA distances (codebook pre-split, L2-direct B-frags);
//   near-tie flagging + fp64 repair => indices == numpy fp64. q is NEVER
//   materialized: conv3 uses LUT[code][pp][tap][cout] (cin pre-contracted
//   with the parity-collapsed weights; row 512 = zeros for boundary).
// Decoder: conv3 = index-gather + LUT adds; conv4 parity-collapsed fp32.
// Outputs d_out (fp32): recon 4194304 | indices 262144 | loss 1
// ---------------------------------------------------------------------------

#define GELUF(v) (0.5f * (v) * (1.0f + erff((v) * 0.70710678118654752440f)))
#define MAXFLAG 262144

typedef __attribute__((ext_vector_type(8))) short short8;
typedef __attribute__((ext_vector_type(4))) float float4v;

static __device__ inline unsigned short f2bf(float f) {
    unsigned u = __float_as_uint(f);
    unsigned r = (u + 0x7FFFu + ((u >> 16) & 1u)) >> 16;
    return (unsigned short)r;
}
static __device__ inline float bf2f(unsigned short h) {
    return __uint_as_float(((unsigned)h) << 16);
}

// conv1 (1->16) + maxpool2 + gelu; output split-bf16 hi/lo [n][y][x][cin].
__global__ __launch_bounds__(256) void k_conv1b(const float* __restrict__ x,
                                                const float* __restrict__ w1,
                                                const float* __restrict__ b1,
                                                unsigned short* __restrict__ h1h,
                                                unsigned short* __restrict__ h1l) {
    int idx = blockIdx.x * 256 + threadIdx.x;
    int xo = idx & 127;
    int yo = (idx >> 7) & 127;
    int n  = idx >> 14;
    const float* xin = x + (size_t)n * 65536;

    float patch[4][4];
    int y0 = 2 * yo - 1, x0 = 2 * xo - 1;
#pragma unroll
    for (int i = 0; i < 4; i++) {
        int iy = y0 + i;
        bool oy = (iy >= 0 && iy < 256);
#pragma unroll
        for (int j = 0; j < 4; j++) {
            int ix = x0 + j;
            patch[i][j] = (oy && ix >= 0 && ix < 256) ? xin[iy * 256 + ix] : 0.0f;
        }
    }
    unsigned short hi[16], lo[16];
#pragma unroll
    for (int c = 0; c < 16; c++) {
        float m = -INFINITY;
#pragma unroll
        for (int sy = 0; sy < 2; sy++)
#pragma unroll
            for (int sx = 0; sx < 2; sx++) {
                float acc = b1[c];
#pragma unroll
                for (int ky = 0; ky < 3; ky++)
#pragma unroll
                    for (int kx = 0; kx < 3; kx++)
                        acc += w1[c * 9 + ky * 3 + kx] * patch[sy + ky][sx + kx];
                m = fmaxf(m, acc);
            }
        float g = GELUF(m);
        hi[c] = f2bf(g);
        lo[c] = f2bf(g - bf2f(hi[c]));
    }
    size_t off = ((size_t)idx) << 4;
    uint ph[8], pl[8];
#pragma unroll
    for (int c2 = 0; c2 < 8; c2++) {
        ph[c2] = (uint)hi[2 * c2] | ((uint)hi[2 * c2 + 1] << 16);
        pl[c2] = (uint)lo[2 * c2] | ((uint)lo[2 * c2 + 1] << 16);
    }
    uint4* dh = (uint4*)(h1h + off);
    uint4* dl = (uint4*)(h1l + off);
    dh[0] = make_uint4(ph[0], ph[1], ph[2], ph[3]);
    dh[1] = make_uint4(ph[4], ph[5], ph[6], ph[7]);
    dl[0] = make_uint4(pl[0], pl[1], pl[2], pl[3]);
    dl[1] = make_uint4(pl[4], pl[5], pl[6], pl[7]);
}

// conv2 (16->32) + maxpool2 via split-bf16 MFMA (unchanged).
__global__ __launch_bounds__(256) void k_conv2m(const unsigned short* __restrict__ h1h,
                                                const unsigned short* __restrict__ h1l,
                                                const unsigned short* __restrict__ w2h,
                                                const unsigned short* __restrict__ w2l,
                                                const float* __restrict__ b2,
                                                float* __restrict__ h2) {
    __shared__ unsigned short s_hi[18 * 2 * 18 * 8];
    __shared__ unsigned short s_lo[18 * 2 * 18 * 8];
    __shared__ unsigned short s_wh[32 * 10 * 2 * 8];
    __shared__ unsigned short s_wl[32 * 10 * 2 * 8];
    __shared__ float s_pool[32 * 64];

    int tid = threadIdx.x;
    int n = blockIdx.x >> 6;
    int tile = blockIdx.x & 63;
    int cx0 = (tile & 7) << 4, cy0 = (tile >> 3) << 4;

    {
        const uint* gh = (const uint*)w2h;
        const uint* gl = (const uint*)w2l;
        uint* dh = (uint*)s_wh; uint* dl = (uint*)s_wl;
        for (int e = tid; e < 2560; e += 256) { dh[e] = gh[e]; dl[e] = gl[e]; }
    }
    {
        const uint* gh = (const uint*)(h1h + (((size_t)n) << 18));
        const uint* gl = (const uint*)(h1l + (((size_t)n) << 18));
        uint* dh = (uint*)s_hi; uint* dl = (uint*)s_lo;
        for (int e = tid; e < 2592; e += 256) {
            int r = e / 144;
            int rem = e - r * 144;
            int c = rem >> 3;
            int dw = rem & 7;
            int y = cy0 - 1 + r, xx = cx0 - 1 + c;
            uint vh = 0, vl = 0;
            if (y >= 0 && y < 128 && xx >= 0 && xx < 128) {
                size_t g = ((size_t)((y << 7) + xx) << 3) + dw;
                vh = gh[g]; vl = gl[g];
            }
            int half = dw >> 2;
            int du = (((r * 2 + half) * 18 + c) << 2) + (dw & 3);
            dh[du] = vh; dl[du] = vl;
        }
    }
    __syncthreads();

    int lane = tid & 63, wid = tid >> 6;
    int m = lane & 15, quad = lane >> 4;
    int tl = quad >> 1, half = quad & 1;

    float4v acc[4][2];
#pragma unroll
    for (int mt = 0; mt < 4; mt++)
#pragma unroll
        for (int nt = 0; nt < 2; nt++)
            acc[mt][nt] = (float4v){0.0f, 0.0f, 0.0f, 0.0f};

    for (int s = 0; s < 5; s++) {
        int tA = (s < 4) ? (2 * s + tl) : 8;
        int tB = (s < 4) ? (2 * s + tl) : (8 + tl);
        short8 Bh[2], Bl[2];
#pragma unroll
        for (int nt = 0; nt < 2; nt++) {
            int u = ((nt * 16 + m) * 10 + tB) * 2 + half;
            Bh[nt] = *(const short8*)(s_wh + (u << 3));
            Bl[nt] = *(const short8*)(s_wl + (u << 3));
        }
        int ky = tA / 3, kx = tA - 3 * (tA / 3);
        short8 Ah[4], Al[4];
#pragma unroll
        for (int mt = 0; mt < 4; mt++) {
            int u = (((wid * 4 + mt + ky) * 2 + half) * 18) + m + kx;
            Ah[mt] = *(const short8*)(s_hi + (u << 3));
            Al[mt] = *(const short8*)(s_lo + (u << 3));
        }
#pragma unroll
        for (int mt = 0; mt < 4; mt++)
#pragma unroll
            for (int nt = 0; nt < 2; nt++) {
                float4v z = acc[mt][nt];
                z = __builtin_amdgcn_mfma_f32_16x16x32_bf16(Al[mt], Bh[nt], z, 0, 0, 0);
                z = __builtin_amdgcn_mfma_f32_16x16x32_bf16(Ah[mt], Bl[nt], z, 0, 0, 0);
                z = __builtin_amdgcn_mfma_f32_16x16x32_bf16(Ah[mt], Bh[nt], z, 0, 0, 0);
                acc[mt][nt] = z;
            }
    }

#pragma unroll
    for (int nt = 0; nt < 2; nt++) {
        int cout = nt * 16 + m;
        float bias = b2[cout];
#pragma unroll
        for (int mtp = 0; mtp < 2; mtp++) {
            float4v a0 = acc[2 * mtp][nt], a1 = acc[2 * mtp + 1][nt];
            float p0 = fmaxf(fmaxf(a0[0], a0[1]), fmaxf(a1[0], a1[1])) + bias;
            float p1 = fmaxf(fmaxf(a0[2], a0[3]), fmaxf(a1[2], a1[3])) + bias;
            int py = wid * 2 + mtp;
            int px = quad * 2;
            s_pool[cout * 64 + py * 8 + px]     = p0;
            s_pool[cout * 64 + py * 8 + px + 1] = p1;
        }
    }
    __syncthreads();
    {
        int c = tid >> 3, pr = tid & 7;
        float* dst = h2 + (((size_t)(n * 32 + c)) << 12) + ((cy0 >> 1) + pr) * 64 + (cx0 >> 1);
        const float4* src = (const float4*)(s_pool + c * 64 + pr * 8);
        ((float4*)dst)[0] = src[0];
        ((float4*)dst)[1] = src[1];
    }
}

// VQ via split-bf16 MFMA; no q materialization (conv3 uses the LUT).
__global__ __launch_bounds__(256) void k_vq_mfma(const float* __restrict__ h2,
                                                 const unsigned short* __restrict__ cbh,
                                                 const unsigned short* __restrict__ cbl,
                                                 const float* __restrict__ c2g,
                                                 float* __restrict__ idx_out,
                                                 float* __restrict__ loss_out,
                                                 int* __restrict__ nflag,
                                                 int* __restrict__ flags) {
    __shared__ float s_best[256], s_best2[256];
    __shared__ int   s_bi[256];
    __shared__ float wsum[4];

    int tid = threadIdx.x;
    int lane = tid & 63;
    int wid  = tid >> 6;
    int m    = lane & 15;
    int quad = lane >> 4;

    int img = blockIdx.x >> 4;
    int sp0 = (blockIdx.x & 15) << 8;
    const float* xb = h2 + ((size_t)(img * 32) << 12) + sp0;

    short8 Ahi[4], Alo[4];
    float x2r[4][4];
    float x2own[4];
#pragma unroll
    for (int mt = 0; mt < 4; mt++) {
        const float* xp = xb + wid * 64 + mt * 16 + m;
        float x2 = 0.0f;
#pragma unroll
        for (int j = 0; j < 8; j++) {
            float fe = xp[(size_t)(quad * 8 + j) << 12];
            x2 += fe * fe;
            unsigned short hi = f2bf(fe);
            unsigned short lo = f2bf(fe - bf2f(hi));
            Ahi[mt][j] = (short)hi;
            Alo[mt][j] = (short)lo;
        }
        x2 += __shfl_xor(x2, 16);
        x2 += __shfl_xor(x2, 32);
        x2own[mt] = x2;
    }
#pragma unroll
    for (int mt = 0; mt < 4; mt++)
#pragma unroll
        for (int r = 0; r < 4; r++)
            x2r[mt][r] = __shfl(x2own[mt], quad * 4 + r);

    float best[4][4], best2[4][4];
    int bi[4][4];
#pragma unroll
    for (int mt = 0; mt < 4; mt++)
#pragma unroll
        for (int r = 0; r < 4; r++) {
            best[mt][r] = INFINITY; best2[mt][r] = INFINITY; bi[mt][r] = 0;
        }

    size_t boff = ((size_t)m << 5) + (quad << 3);
    short8 Bh = *(const short8*)(cbh + boff);
    short8 Bl = *(const short8*)(cbl + boff);
    float  c2v = c2g[m];

    for (int nt = 0; nt < 32; nt++) {
        short8 curBh = Bh, curBl = Bl;
        float  curc2 = c2v;
        if (nt < 31) {
            size_t o = boff + ((size_t)(nt + 1) << 9);
            Bh = *(const short8*)(cbh + o);
            Bl = *(const short8*)(cbl + o);
            c2v = c2g[(nt + 1) * 16 + m];
        }
        int ncode = nt * 16 + m;

        float4v acc[4];
#pragma unroll
        for (int mt = 0; mt < 4; mt++) {
            float4v z = {0.0f, 0.0f, 0.0f, 0.0f};
            z = __builtin_amdgcn_mfma_f32_16x16x32_bf16(Alo[mt], curBh, z, 0, 0, 0);
            z = __builtin_amdgcn_mfma_f32_16x16x32_bf16(Ahi[mt], curBl, z, 0, 0, 0);
            z = __builtin_amdgcn_mfma_f32_16x16x32_bf16(Ahi[mt], curBh, z, 0, 0, 0);
            acc[mt] = z;
        }
#pragma unroll
        for (int mt = 0; mt < 4; mt++)
#pragma unroll
            for (int r = 0; r < 4; r++) {
                float dist = fmaf(acc[mt][r], -2.0f, curc2);
                best2[mt][r] = fminf(best2[mt][r], fmaxf(dist, best[mt][r]));
                bool lt = dist < best[mt][r];
                bi[mt][r] = lt ? ncode : bi[mt][r];
                best[mt][r] = fminf(best[mt][r], dist);
            }
    }

#pragma unroll
    for (int mt = 0; mt < 4; mt++)
#pragma unroll
        for (int r = 0; r < 4; r++) {
            float b1v = best[mt][r], b2v = best2[mt][r];
            int   biv = bi[mt][r];
#pragma unroll
            for (int mask = 1; mask < 16; mask <<= 1) {
                float ob = __shfl_xor(b1v, mask);
                float ob2 = __shfl_xor(b2v, mask);
                int   obi = __shfl_xor(biv, mask);
                b2v = fminf(fminf(b2v, ob2), fmaxf(b1v, ob));
                if (ob < b1v || (ob == b1v && obi < biv)) { b1v = ob; biv = obi; }
            }
            if (m == 0) {
                int p = wid * 64 + mt * 16 + quad * 4 + r;
                s_best[p] = b1v + x2r[mt][r];
                s_best2[p] = b2v + x2r[mt][r];
                s_bi[p] = biv;
            }
        }
    __syncthreads();

    int pos = blockIdx.x * 256 + tid;
    float bb = s_best[tid], bb2 = s_best2[tid];
    int   kk = s_bi[tid];
    idx_out[pos] = (float)kk;

    float eps = 0.02f + 0.0005f * fabsf(bb);
    if (bb2 - bb < eps) {
        int slot = atomicAdd(nflag, 1);
        if (slot < MAXFLAG) flags[slot] = pos;
    }

    float lsum = fmaxf(bb, 0.0f);
#pragma unroll
    for (int o = 32; o > 0; o >>= 1) lsum += __shfl_down(lsum, o);
    if (lane == 0) wsum[wid] = lsum;
    __syncthreads();
    if (tid == 0)
        atomicAdd(loss_out, (wsum[0] + wsum[1] + wsum[2] + wsum[3]) * (1.0f / 8388608.0f));
}

// LUT[code][pp][tap][cout] = sum_cin wc3[pp][cin][tap][cout] * cb[code][cin];
// row 512 = zeros (boundary). grid 513, 256 threads (t = pp*64+tap*16+cout).
__global__ __launch_bounds__(256) void k_lut(const float* __restrict__ wc3,
                                             const float* __restrict__ cb,
                                             float* __restrict__ lut) {
    int code = blockIdx.x;
    int t = threadIdx.x;
    float s = 0.0f;
    if (code < 512) {
        int pp = t >> 6, rem = t & 63;
        const float* wp = wc3 + pp * 2048 + rem;
        const float* cr = cb + code * 32;
        for (int cin = 0; cin < 32; cin++)
            s += wp[cin * 64] * cr[cin];
    }
    lut[(size_t)code * 256 + t] = s;
}

// fp64 repair: fixes idx_out only (q not materialized).
__global__ __launch_bounds__(64) void k_repair(const float* __restrict__ x,
                                               const float* __restrict__ w1,
                                               const float* __restrict__ b1,
                                               const float* __restrict__ w2,
                                               const float* __restrict__ b2,
                                               const float* __restrict__ cb,
                                               float* __restrict__ idx_out,
                                               const int* __restrict__ nflag,
                                               const int* __restrict__ flags) {
    __shared__ double h1w[16][16];
    __shared__ double xvd[32];
    int lane = threadIdx.x;
    int cnt = *nflag;
    if (cnt > MAXFLAG) cnt = MAXFLAG;

    for (int fi = blockIdx.x; fi < cnt; fi += gridDim.x) {
        int pos = flags[fi];
        int n = pos >> 12, sp = pos & 4095, yo = sp >> 6, xo = sp & 63;

        int pix = lane >> 2, cg = lane & 3;
        int dy = pix >> 2, dx = pix & 3;
        int yh = 2 * yo - 1 + dy, xh = 2 * xo - 1 + dx;
        double hv[4] = {0.0, 0.0, 0.0, 0.0};
        if (yh >= 0 && yh < 128 && xh >= 0 && xh < 128) {
            const float* xin = x + (size_t)n * 65536;
            double patch[4][4];
            int y0 = 2 * yh - 1, x0 = 2 * xh - 1;
#pragma unroll
            for (int i = 0; i < 4; i++) {
                int iy = y0 + i;
                bool oy = (iy >= 0 && iy < 256);
#pragma unroll
                for (int j = 0; j < 4; j++) {
                    int ix = x0 + j;
                    patch[i][j] = (oy && ix >= 0 && ix < 256) ? (double)xin[iy * 256 + ix] : 0.0;
                }
            }
#pragma unroll
            for (int j = 0; j < 4; j++) {
                int c = cg * 4 + j;
                double mm = -INFINITY;
#pragma unroll
                for (int sy = 0; sy < 2; sy++)
#pragma unroll
                    for (int sx = 0; sx < 2; sx++) {
                        double acc = (double)b1[c];
#pragma unroll
                        for (int ky = 0; ky < 3; ky++)
#pragma unroll
                            for (int kx = 0; kx < 3; kx++)
                                acc += (double)w1[c * 9 + ky * 3 + kx] * patch[sy + ky][sx + kx];
                        mm = fmax(mm, acc);
                    }
                hv[j] = 0.5 * mm * (1.0 + erf(mm * 0.70710678118654752440));
            }
        }
        __syncthreads();
#pragma unroll
        for (int j = 0; j < 4; j++) h1w[cg * 4 + j][pix] = hv[j];
        __syncthreads();

        if (lane < 32) {
            double bb = (double)b2[lane];
            double acc[2][2] = {{bb, bb}, {bb, bb}};
            for (int cin = 0; cin < 16; cin++)
#pragma unroll
                for (int ky = 0; ky < 3; ky++)
#pragma unroll
                    for (int kx = 0; kx < 3; kx++) {
                        double wv = (double)w2[((lane * 16 + cin) * 3 + ky) * 3 + kx];
#pragma unroll
                        for (int sy = 0; sy < 2; sy++)
#pragma unroll
                            for (int sx = 0; sx < 2; sx++)
                                acc[sy][sx] += wv * h1w[cin][(sy + ky) * 4 + (sx + kx)];
                    }
            xvd[lane] = fmax(fmax(acc[0][0], acc[0][1]), fmax(acc[1][0], acc[1][1]));
        }
        __syncthreads();

        double x2 = 0.0;
        for (int d = 0; d < 32; d++) x2 += xvd[d] * xvd[d];
        double best = INFINITY;
        int bi = 0;
        for (int j = 0; j < 8; j++) {
            int k = lane * 8 + j;
            const float* cp = cb + k * 32;
            double c2 = 0.0, dot = 0.0;
#pragma unroll
            for (int d = 0; d < 32; d++) {
                double cd = (double)cp[d];
                c2 += cd * cd;
                dot += xvd[d] * cd;
            }
            double dist = x2 - 2.0 * dot + c2;
            if (dist < best) { best = dist; bi = k; }
        }
#pragma unroll
        for (int o = 32; o > 0; o >>= 1) {
            double od = __shfl_down(best, o);
            int oi = __shfl_down(bi, o);
            if (od < best || (od == best && oi < bi)) { best = od; bi = oi; }
        }
        bi = __shfl(bi, 0);

        if (lane == 0) idx_out[(size_t)n * 4096 + sp] = (float)bi;
    }
}

// prep: parity decoder weights + split-bf16 conv2 weights + split codebook.
__global__ __launch_bounds__(256) void k_prep(const float* __restrict__ w2,
                                              const float* __restrict__ w3,
                                              const float* __restrict__ w4,
                                              const float* __restrict__ cb,
                                              unsigned short* __restrict__ w2h,
                                              unsigned short* __restrict__ w2l,
                                              float* __restrict__ wc3,
                                              float* __restrict__ wc4,
                                              unsigned short* __restrict__ cbh,
                                              unsigned short* __restrict__ cbl,
                                              float* __restrict__ c2g) {
    const int masks[2][2] = {{1, 6}, {3, 4}};
    for (int e = threadIdx.x; e < 8192; e += 256) {
        int cout = e & 15, tap = (e >> 4) & 3, cin = (e >> 6) & 31, pp = e >> 11;
        int rm = masks[pp >> 1][tap >> 1], cm = masks[pp & 1][tap & 1];
        float s = 0.0f;
        for (int ky = 0; ky < 3; ky++)
            if ((rm >> ky) & 1)
                for (int kx = 0; kx < 3; kx++)
                    if ((cm >> kx) & 1) s += w3[(cout * 32 + cin) * 9 + ky * 3 + kx];
        wc3[e] = s;
    }
    for (int e = threadIdx.x; e < 1024; e += 256) {
        int tap = e & 3, cin = (e >> 2) & 15, pp = e >> 6;
        int rm = masks[pp >> 1][tap >> 1], cm = masks[pp & 1][tap & 1];
        float s = 0.0f;
        for (int ky = 0; ky < 3; ky++)
            if ((rm >> ky) & 1)
                for (int kx = 0; kx < 3; kx++)
                    if ((cm >> kx) & 1) s += w4[cin * 9 + ky * 3 + kx];
        wc4[e] = s;
    }
    for (int e = threadIdx.x; e < 5120; e += 256) {
        int cout = e / 160;
        int rem = e - cout * 160;
        int tap = rem >> 4;
        int cin = rem & 15;
        float v = 0.0f;
        if (tap < 9) {
            int ky = tap / 3, kx = tap - 3 * (tap / 3);
            v = w2[((cout * 16 + cin) * 3 + ky) * 3 + kx];
        }
        unsigned short hi = f2bf(v);
        unsigned short lo = f2bf(v - bf2f(hi));
        w2h[e] = hi;
        w2l[e] = lo;
    }
    for (int e = threadIdx.x; e < 16384; e += 256) {
        float v = cb[e];
        unsigned short hi = f2bf(v);
        cbh[e] = hi;
        cbl[e] = f2bf(v - bf2f(hi));
    }
    for (int k = threadIdx.x; k < 512; k += 256) {
        float c2 = 0.0f;
#pragma unroll
        for (int d = 0; d < 32; d++) {
            float fe = cb[k * 32 + d];
            c2 += fe * fe;
        }
        c2g[k] = c2;
    }
}

// up2+conv3(32->16)+gelu via code LUT: 9 neighbor indices, pure LUT adds.
__global__ __launch_bounds__(256) void k_conv3L(const float* __restrict__ idxf,
                                                const float* __restrict__ lut,
                                                const float* __restrict__ b3,
                                                float* __restrict__ h3) {
    int t = blockIdx.x * 256 + threadIdx.x;
    int b = t & 63, a = (t >> 6) & 63, n = t >> 12;
    const float* ib = idxf + ((size_t)n << 12);

    int code[3][3];
#pragma unroll
    for (int r = 0; r < 3; r++) {
        int qy = a - 1 + r;
        bool vy = (qy >= 0 && qy < 64);
#pragma unroll
        for (int cc = 0; cc < 3; cc++) {
            int qx = b - 1 + cc;
            code[r][cc] = (vy && qx >= 0 && qx < 64) ? (int)ib[(qy << 6) + qx] : 512;
        }
    }

    float acc[2][2][16];
#pragma unroll
    for (int c = 0; c < 16; c++) {
        float bv = b3[c];
        acc[0][0][c] = bv; acc[0][1][c] = bv; acc[1][0][c] = bv; acc[1][1][c] = bv;
    }

#pragma unroll
    for (int r = 0; r < 3; r++)
#pragma unroll
        for (int cc = 0; cc < 3; cc++) {
            const float* base = lut + (size_t)code[r][cc] * 256;
#pragma unroll
            for (int dy = 0; dy < 2; dy++) {
                int py = r - dy;
                if (py < 0 || py > 1) continue;
#pragma unroll
                for (int dx = 0; dx < 2; dx++) {
                    int px = cc - dx;
                    if (px < 0 || px > 1) continue;
                    const float4* lp = (const float4*)(base + (py * 2 + px) * 64 + (dy * 2 + dx) * 16);
#pragma unroll
                    for (int j = 0; j < 4; j++) {
                        float4 w = lp[j];
                        acc[py][px][4 * j + 0] += w.x;
                        acc[py][px][4 * j + 1] += w.y;
                        acc[py][px][4 * j + 2] += w.z;
                        acc[py][px][4 * j + 3] += w.w;
                    }
                }
            }
        }

#pragma unroll
    for (int c = 0; c < 16; c++)
#pragma unroll
        for (int py = 0; py < 2; py++) {
            float2 f2 = make_float2(GELUF(acc[py][0][c]), GELUF(acc[py][1][c]));
            *(float2*)(h3 + ((size_t)(n * 16 + c) << 14) + ((2 * a + py) << 7) + 2 * b) = f2;
        }
}

// up2+conv4(16->1)+clip, parity-collapsed (unchanged).
__global__ __launch_bounds__(256) void k_conv4n(const float* __restrict__ h3,
                                                const float* __restrict__ wc4,
                                                const float* __restrict__ b4,
                                                float* __restrict__ out) {
    int t = blockIdx.x * 256 + threadIdx.x;
    int b = t & 127, a = (t >> 7) & 127, n = t >> 14;

    float bv = b4[0];
    float acc[2][2] = {{bv, bv}, {bv, bv}};

    for (int cin = 0; cin < 16; cin++) {
        const float* hc = h3 + ((size_t)(n * 16 + cin) << 14);
        float v[3][3];
#pragma unroll
        for (int r = 0; r < 3; r++) {
            int hy = a - 1 + r;
            bool vy = (hy >= 0 && hy < 128);
#pragma unroll
            for (int cc = 0; cc < 3; cc++) {
                int hx = b - 1 + cc;
                v[r][cc] = (vy && hx >= 0 && hx < 128) ? hc[(hy << 7) + hx] : 0.0f;
            }
        }
#pragma unroll
        for (int py = 0; py < 2; py++)
#pragma unroll
            for (int px = 0; px < 2; px++)
#pragma unroll
                for (int dy = 0; dy < 2; dy++)
#pragma unroll
                    for (int dx = 0; dx < 2; dx++)
                        acc[py][px] += wc4[(py * 2 + px) * 64 + cin * 4 + dy * 2 + dx] *
                                       v[py + dy][px + dx];
    }
#pragma unroll
    for (int py = 0; py < 2; py++) {
        float2 f2 = make_float2(fminf(fmaxf(acc[py][0], -1.0f), 1.0f),
                                fminf(fmaxf(acc[py][1], -1.0f), 1.0f));
        *(float2*)(out + (size_t)n * 65536 + (2 * a + py) * 256 + 2 * b) = f2;
    }
}

extern "C" void kernel_launch(void* const* d_in, const int* in_sizes, int n_in,
                              void* d_out, int out_size, void* d_ws, size_t ws_size,
                              hipStream_t stream) {
    const float* x  = (const float*)d_in[0];
    const float* w1 = (const float*)d_in[1];
    const float* b1 = (const float*)d_in[2];
    const float* w2 = (const float*)d_in[3];
    const float* b2 = (const float*)d_in[4];
    const float* cb = (const float*)d_in[5];
    const float* w3 = (const float*)d_in[6];
    const float* b3 = (const float*)d_in[7];
    const float* w4 = (const float*)d_in[8];
    const float* b4 = (const float*)d_in[9];

    float* out      = (float*)d_out;
    float* idx_out  = out + 4194304;
    float* loss_out = out + 4194304 + 262144;

    char* ws = (char*)d_ws;
    unsigned short* h1h = (unsigned short*)ws;                      // [0,32M)
    unsigned short* h1l = (unsigned short*)(ws + (size_t)33554432); // [32M,64M)
    float* h2  = (float*)(ws + (size_t)67108864);                   // [64M,96M)
    float* h3  = (float*)ws;                                        // [0,64M) after conv2
    float* lut = (float*)(ws + (size_t)67108864);                   // 525 KB over dead h2
    size_t T = 100663296;
    float* wc3 = (float*)(ws + T);                             // 32 KB
    float* wc4 = (float*)(ws + T + 32768);                     // 4 KB
    unsigned short* w2h = (unsigned short*)(ws + T + 36864);   // 10240 B
    unsigned short* w2l = (unsigned short*)(ws + T + 47104);   // 10240 B
    int* nflag = (int*)(ws + T + 57344);
    int* flags = (int*)(ws + T + 57408);                       // 1 MB
    size_t T2 = T + 57408 + 1048576;
    unsigned short* cbh = (unsigned short*)(ws + T2);          // 32 KB
    unsigned short* cbl = (unsigned short*)(ws + T2 + 32768);  // 32 KB
    float* c2g = (float*)(ws + T2 + 65536);                    // 2 KB

    (void)hipMemsetAsync(loss_out, 0, 4, stream);
    (void)hipMemsetAsync(nflag, 0, 4, stream);

    k_prep<<<1, 256, 0, stream>>>(w2, w3, w4, cb, w2h, w2l, wc3, wc4, cbh, cbl, c2g);
    k_conv1b<<<4096, 256, 0, stream>>>(x, w1, b1, h1h, h1l);
    k_conv2m<<<4096, 256, 0, stream>>>(h1h, h1l, w2h, w2l, b2, h2);
    k_vq_mfma<<<1024, 256, 0, stream>>>(h2, cbh, cbl, c2g, idx_out, loss_out, nflag, flags);
    k_lut<<<513, 256, 0, stream>>>(wc3, cb, lut);   // into dead h2 region (after vq)
    k_repair<<<16384, 64, 0, stream>>>(x, w1, b1, w2, b2, cb, idx_out, nflag, flags);
    k_conv3L<<<1024, 256, 0, stream>>>(idx_out, lut, b3, h3);
    k_conv4n<<<4096, 256, 0, stream>>>(h3, wc4, b4, out);
}

// Round 11
// 410.656 us; speedup vs baseline: 1.1662x; 1.1267x over previous
//
#include <hip/hip_runtime.h>
#include <math.h>

// ---------------------------------------------------------------------------
// SimpleVQAutoEncoder forward.
// conv1 -> h1 split-bf16 hi/lo [n][y][x][cin]; conv2 split-bf16 MFMA GEMM.
// VQ: split-bf16 MFMA distances (codebook pre-split, L2-direct B-frags);
//   near-tie flagging + fp64 repair => indices == numpy fp64. q is NEVER
//   materialized: decoder uses LUT[code][pp][tap][cout].
// Decoder: single fused kernel k_dec — LUT adds -> gelu h3 tile in LDS ->
//   parity-collapsed conv4 -> clip -> out. No h3 global round-trip.
// Outputs d_out (fp32): recon 4194304 | indices 262144 | loss 1
// ---------------------------------------------------------------------------

#define GELUF(v) (0.5f * (v) * (1.0f + erff((v) * 0.70710678118654752440f)))
#define MAXFLAG 262144

typedef __attribute__((ext_vector_type(8))) short short8;
typedef __attribute__((ext_vector_type(4))) float float4v;

static __device__ inline unsigned short f2bf(float f) {
    unsigned u = __float_as_uint(f);
    unsigned r = (u + 0x7FFFu + ((u >> 16) & 1u)) >> 16;
    return (unsigned short)r;
}
static __device__ inline float bf2f(unsigned short h) {
    return __uint_as_float(((unsigned)h) << 16);
}

// conv1 (1->16) + maxpool2 + gelu; output split-bf16 hi/lo [n][y][x][cin].
__global__ __launch_bounds__(256) void k_conv1b(const float* __restrict__ x,
                                                const float* __restrict__ w1,
                                                const float* __restrict__ b1,
                                                unsigned short* __restrict__ h1h,
                                                unsigned short* __restrict__ h1l) {
    int idx = blockIdx.x * 256 + threadIdx.x;
    int xo = idx & 127;
    int yo = (idx >> 7) & 127;
    int n  = idx >> 14;
    const float* xin = x + (size_t)n * 65536;

    float patch[4][4];
    int y0 = 2 * yo - 1, x0 = 2 * xo - 1;
#pragma unroll
    for (int i = 0; i < 4; i++) {
        int iy = y0 + i;
        bool oy = (iy >= 0 && iy < 256);
#pragma unroll
        for (int j = 0; j < 4; j++) {
            int ix = x0 + j;
            patch[i][j] = (oy && ix >= 0 && ix < 256) ? xin[iy * 256 + ix] : 0.0f;
        }
    }
    unsigned short hi[16], lo[16];
#pragma unroll
    for (int c = 0; c < 16; c++) {
        float m = -INFINITY;
#pragma unroll
        for (int sy = 0; sy < 2; sy++)
#pragma unroll
            for (int sx = 0; sx < 2; sx++) {
                float acc = b1[c];
#pragma unroll
                for (int ky = 0; ky < 3; ky++)
#pragma unroll
                    for (int kx = 0; kx < 3; kx++)
                        acc += w1[c * 9 + ky * 3 + kx] * patch[sy + ky][sx + kx];
                m = fmaxf(m, acc);
            }
        float g = GELUF(m);
        hi[c] = f2bf(g);
        lo[c] = f2bf(g - bf2f(hi[c]));
    }
    size_t off = ((size_t)idx) << 4;
    uint ph[8], pl[8];
#pragma unroll
    for (int c2 = 0; c2 < 8; c2++) {
        ph[c2] = (uint)hi[2 * c2] | ((uint)hi[2 * c2 + 1] << 16);
        pl[c2] = (uint)lo[2 * c2] | ((uint)lo[2 * c2 + 1] << 16);
    }
    uint4* dh = (uint4*)(h1h + off);
    uint4* dl = (uint4*)(h1l + off);
    dh[0] = make_uint4(ph[0], ph[1], ph[2], ph[3]);
    dh[1] = make_uint4(ph[4], ph[5], ph[6], ph[7]);
    dl[0] = make_uint4(pl[0], pl[1], pl[2], pl[3]);
    dl[1] = make_uint4(pl[4], pl[5], pl[6], pl[7]);
}

// conv2 (16->32) + maxpool2 via split-bf16 MFMA (unchanged).
__global__ __launch_bounds__(256) void k_conv2m(const unsigned short* __restrict__ h1h,
                                                const unsigned short* __restrict__ h1l,
                                                const unsigned short* __restrict__ w2h,
                                                const unsigned short* __restrict__ w2l,
                                                const float* __restrict__ b2,
                                                float* __restrict__ h2) {
    __shared__ unsigned short s_hi[18 * 2 * 18 * 8];
    __shared__ unsigned short s_lo[18 * 2 * 18 * 8];
    __shared__ unsigned short s_wh[32 * 10 * 2 * 8];
    __shared__ unsigned short s_wl[32 * 10 * 2 * 8];
    __shared__ float s_pool[32 * 64];

    int tid = threadIdx.x;
    int n = blockIdx.x >> 6;
    int tile = blockIdx.x & 63;
    int cx0 = (tile & 7) << 4, cy0 = (tile >> 3) << 4;

    {
        const uint* gh = (const uint*)w2h;
        const uint* gl = (const uint*)w2l;
        uint* dh = (uint*)s_wh; uint* dl = (uint*)s_wl;
        for (int e = tid; e < 2560; e += 256) { dh[e] = gh[e]; dl[e] = gl[e]; }
    }
    {
        const uint* gh = (const uint*)(h1h + (((size_t)n) << 18));
        const uint* gl = (const uint*)(h1l + (((size_t)n) << 18));
        uint* dh = (uint*)s_hi; uint* dl = (uint*)s_lo;
        for (int e = tid; e < 2592; e += 256) {
            int r = e / 144;
            int rem = e - r * 144;
            int c = rem >> 3;
            int dw = rem & 7;
            int y = cy0 - 1 + r, xx = cx0 - 1 + c;
            uint vh = 0, vl = 0;
            if (y >= 0 && y < 128 && xx >= 0 && xx < 128) {
                size_t g = ((size_t)((y << 7) + xx) << 3) + dw;
                vh = gh[g]; vl = gl[g];
            }
            int half = dw >> 2;
            int du = (((r * 2 + half) * 18 + c) << 2) + (dw & 3);
            dh[du] = vh; dl[du] = vl;
        }
    }
    __syncthreads();

    int lane = tid & 63, wid = tid >> 6;
    int m = lane & 15, quad = lane >> 4;
    int tl = quad >> 1, half = quad & 1;

    float4v acc[4][2];
#pragma unroll
    for (int mt = 0; mt < 4; mt++)
#pragma unroll
        for (int nt = 0; nt < 2; nt++)
            acc[mt][nt] = (float4v){0.0f, 0.0f, 0.0f, 0.0f};

    for (int s = 0; s < 5; s++) {
        int tA = (s < 4) ? (2 * s + tl) : 8;
        int tB = (s < 4) ? (2 * s + tl) : (8 + tl);
        short8 Bh[2], Bl[2];
#pragma unroll
        for (int nt = 0; nt < 2; nt++) {
            int u = ((nt * 16 + m) * 10 + tB) * 2 + half;
            Bh[nt] = *(const short8*)(s_wh + (u << 3));
            Bl[nt] = *(const short8*)(s_wl + (u << 3));
        }
        int ky = tA / 3, kx = tA - 3 * (tA / 3);
        short8 Ah[4], Al[4];
#pragma unroll
        for (int mt = 0; mt < 4; mt++) {
            int u = (((wid * 4 + mt + ky) * 2 + half) * 18) + m + kx;
            Ah[mt] = *(const short8*)(s_hi + (u << 3));
            Al[mt] = *(const short8*)(s_lo + (u << 3));
        }
#pragma unroll
        for (int mt = 0; mt < 4; mt++)
#pragma unroll
            for (int nt = 0; nt < 2; nt++) {
                float4v z = acc[mt][nt];
                z = __builtin_amdgcn_mfma_f32_16x16x32_bf16(Al[mt], Bh[nt], z, 0, 0, 0);
                z = __builtin_amdgcn_mfma_f32_16x16x32_bf16(Ah[mt], Bl[nt], z, 0, 0, 0);
                z = __builtin_amdgcn_mfma_f32_16x16x32_bf16(Ah[mt], Bh[nt], z, 0, 0, 0);
                acc[mt][nt] = z;
            }
    }

#pragma unroll
    for (int nt = 0; nt < 2; nt++) {
        int cout = nt * 16 + m;
        float bias = b2[cout];
#pragma unroll
        for (int mtp = 0; mtp < 2; mtp++) {
            float4v a0 = acc[2 * mtp][nt], a1 = acc[2 * mtp + 1][nt];
            float p0 = fmaxf(fmaxf(a0[0], a0[1]), fmaxf(a1[0], a1[1])) + bias;
            float p1 = fmaxf(fmaxf(a0[2], a0[3]), fmaxf(a1[2], a1[3])) + bias;
            int py = wid * 2 + mtp;
            int px = quad * 2;
            s_pool[cout * 64 + py * 8 + px]     = p0;
            s_pool[cout * 64 + py * 8 + px + 1] = p1;
        }
    }
    __syncthreads();
    {
        int c = tid >> 3, pr = tid & 7;
        float* dst = h2 + (((size_t)(n * 32 + c)) << 12) + ((cy0 >> 1) + pr) * 64 + (cx0 >> 1);
        const float4* src = (const float4*)(s_pool + c * 64 + pr * 8);
        ((float4*)dst)[0] = src[0];
        ((float4*)dst)[1] = src[1];
    }
}

// VQ via split-bf16 MFMA; block = 128 threads (2 waves) for occupancy slack.
__global__ __launch_bounds__(128) void k_vq_mfma(const float* __restrict__ h2,
                                                 const unsigned short* __restrict__ cbh,
                                                 const unsigned short* __restrict__ cbl,
                                                 const float* __restrict__ c2g,
                                                 float* __restrict__ idx_out,
                                                 float* __restrict__ loss_out,
                                                 int* __restrict__ nflag,
                                                 int* __restrict__ flags) {
    __shared__ float s_best[128], s_best2[128];
    __shared__ int   s_bi[128];
    __shared__ float wsum[2];

    int tid = threadIdx.x;
    int lane = tid & 63;
    int wid  = tid >> 6;
    int m    = lane & 15;
    int quad = lane >> 4;

    int img = blockIdx.x >> 5;                 // 32 blocks per image
    int sp0 = (blockIdx.x & 31) << 7;          // 128 positions within image
    const float* xb = h2 + ((size_t)(img * 32) << 12) + sp0;

    short8 Ahi[4], Alo[4];
    float x2r[4][4];
    float x2own[4];
#pragma unroll
    for (int mt = 0; mt < 4; mt++) {
        const float* xp = xb + wid * 64 + mt * 16 + m;
        float x2 = 0.0f;
#pragma unroll
        for (int j = 0; j < 8; j++) {
            float fe = xp[(size_t)(quad * 8 + j) << 12];
            x2 += fe * fe;
            unsigned short hi = f2bf(fe);
            unsigned short lo = f2bf(fe - bf2f(hi));
            Ahi[mt][j] = (short)hi;
            Alo[mt][j] = (short)lo;
        }
        x2 += __shfl_xor(x2, 16);
        x2 += __shfl_xor(x2, 32);
        x2own[mt] = x2;
    }
#pragma unroll
    for (int mt = 0; mt < 4; mt++)
#pragma unroll
        for (int r = 0; r < 4; r++)
            x2r[mt][r] = __shfl(x2own[mt], quad * 4 + r);

    float best[4][4], best2[4][4];
    int bi[4][4];
#pragma unroll
    for (int mt = 0; mt < 4; mt++)
#pragma unroll
        for (int r = 0; r < 4; r++) {
            best[mt][r] = INFINITY; best2[mt][r] = INFINITY; bi[mt][r] = 0;
        }

    size_t boff = ((size_t)m << 5) + (quad << 3);
    short8 Bh = *(const short8*)(cbh + boff);
    short8 Bl = *(const short8*)(cbl + boff);
    float  c2v = c2g[m];

    for (int nt = 0; nt < 32; nt++) {
        short8 curBh = Bh, curBl = Bl;
        float  curc2 = c2v;
        if (nt < 31) {
            size_t o = boff + ((size_t)(nt + 1) << 9);
            Bh = *(const short8*)(cbh + o);
            Bl = *(const short8*)(cbl + o);
            c2v = c2g[(nt + 1) * 16 + m];
        }
        int ncode = nt * 16 + m;

        float4v acc[4];
#pragma unroll
        for (int mt = 0; mt < 4; mt++) {
            float4v z = {0.0f, 0.0f, 0.0f, 0.0f};
            z = __builtin_amdgcn_mfma_f32_16x16x32_bf16(Alo[mt], curBh, z, 0, 0, 0);
            z = __builtin_amdgcn_mfma_f32_16x16x32_bf16(Ahi[mt], curBl, z, 0, 0, 0);
            z = __builtin_amdgcn_mfma_f32_16x16x32_bf16(Ahi[mt], curBh, z, 0, 0, 0);
            acc[mt] = z;
        }
#pragma unroll
        for (int mt = 0; mt < 4; mt++)
#pragma unroll
            for (int r = 0; r < 4; r++) {
                float dist = fmaf(acc[mt][r], -2.0f, curc2);
                best2[mt][r] = fminf(best2[mt][r], fmaxf(dist, best[mt][r]));
                bool lt = dist < best[mt][r];
                bi[mt][r] = lt ? ncode : bi[mt][r];
                best[mt][r] = fminf(best[mt][r], dist);
            }
    }

#pragma unroll
    for (int mt = 0; mt < 4; mt++)
#pragma unroll
        for (int r = 0; r < 4; r++) {
            float b1v = best[mt][r], b2v = best2[mt][r];
            int   biv = bi[mt][r];
#pragma unroll
            for (int mask = 1; mask < 16; mask <<= 1) {
                float ob = __shfl_xor(b1v, mask);
                float ob2 = __shfl_xor(b2v, mask);
                int   obi = __shfl_xor(biv, mask);
                b2v = fminf(fminf(b2v, ob2), fmaxf(b1v, ob));
                if (ob < b1v || (ob == b1v && obi < biv)) { b1v = ob; biv = obi; }
            }
            if (m == 0) {
                int p = wid * 64 + mt * 16 + quad * 4 + r;
                s_best[p] = b1v + x2r[mt][r];
                s_best2[p] = b2v + x2r[mt][r];
                s_bi[p] = biv;
            }
        }
    __syncthreads();

    int pos = blockIdx.x * 128 + tid;
    float bb = s_best[tid], bb2 = s_best2[tid];
    int   kk = s_bi[tid];
    idx_out[pos] = (float)kk;

    float eps = 0.02f + 0.0005f * fabsf(bb);
    if (bb2 - bb < eps) {
        int slot = atomicAdd(nflag, 1);
        if (slot < MAXFLAG) flags[slot] = pos;
    }

    float lsum = fmaxf(bb, 0.0f);
#pragma unroll
    for (int o = 32; o > 0; o >>= 1) lsum += __shfl_down(lsum, o);
    if (lane == 0) wsum[wid] = lsum;
    __syncthreads();
    if (tid == 0)
        atomicAdd(loss_out, (wsum[0] + wsum[1]) * (1.0f / 8388608.0f));
}

// LUT[code][pp][tap][cout] = sum_cin wc3[pp][cin][tap][cout] * cb[code][cin];
// row 512 = zeros (boundary). grid 513, 256 threads.
__global__ __launch_bounds__(256) void k_lut(const float* __restrict__ wc3,
                                             const float* __restrict__ cb,
                                             float* __restrict__ lut) {
    int code = blockIdx.x;
    int t = threadIdx.x;
    float s = 0.0f;
    if (code < 512) {
        int pp = t >> 6, rem = t & 63;
        const float* wp = wc3 + pp * 2048 + rem;
        const float* cr = cb + code * 32;
        for (int cin = 0; cin < 32; cin++)
            s += wp[cin * 64] * cr[cin];
    }
    lut[(size_t)code * 256 + t] = s;
}

// fp64 repair: fixes idx_out only (q not materialized).
__global__ __launch_bounds__(64) void k_repair(const float* __restrict__ x,
                                               const float* __restrict__ w1,
                                               const float* __restrict__ b1,
                                               const float* __restrict__ w2,
                                               const float* __restrict__ b2,
                                               const float* __restrict__ cb,
                                               float* __restrict__ idx_out,
                                               const int* __restrict__ nflag,
                                               const int* __restrict__ flags) {
    __shared__ double h1w[16][16];
    __shared__ double xvd[32];
    int lane = threadIdx.x;
    int cnt = *nflag;
    if (cnt > MAXFLAG) cnt = MAXFLAG;

    for (int fi = blockIdx.x; fi < cnt; fi += gridDim.x) {
        int pos = flags[fi];
        int n = pos >> 12, sp = pos & 4095, yo = sp >> 6, xo = sp & 63;

        int pix = lane >> 2, cg = lane & 3;
        int dy = pix >> 2, dx = pix & 3;
        int yh = 2 * yo - 1 + dy, xh = 2 * xo - 1 + dx;
        double hv[4] = {0.0, 0.0, 0.0, 0.0};
        if (yh >= 0 && yh < 128 && xh >= 0 && xh < 128) {
            const float* xin = x + (size_t)n * 65536;
            double patch[4][4];
            int y0 = 2 * yh - 1, x0 = 2 * xh - 1;
#pragma unroll
            for (int i = 0; i < 4; i++) {
                int iy = y0 + i;
                bool oy = (iy >= 0 && iy < 256);
#pragma unroll
                for (int j = 0; j < 4; j++) {
                    int ix = x0 + j;
                    patch[i][j] = (oy && ix >= 0 && ix < 256) ? (double)xin[iy * 256 + ix] : 0.0;
                }
            }
#pragma unroll
            for (int j = 0; j < 4; j++) {
                int c = cg * 4 + j;
                double mm = -INFINITY;
#pragma unroll
                for (int sy = 0; sy < 2; sy++)
#pragma unroll
                    for (int sx = 0; sx < 2; sx++) {
                        double acc = (double)b1[c];
#pragma unroll
                        for (int ky = 0; ky < 3; ky++)
#pragma unroll
                            for (int kx = 0; kx < 3; kx++)
                                acc += (double)w1[c * 9 + ky * 3 + kx] * patch[sy + ky][sx + kx];
                        mm = fmax(mm, acc);
                    }
                hv[j] = 0.5 * mm * (1.0 + erf(mm * 0.70710678118654752440));
            }
        }
        __syncthreads();
#pragma unroll
        for (int j = 0; j < 4; j++) h1w[cg * 4 + j][pix] = hv[j];
        __syncthreads();

        if (lane < 32) {
            double bb = (double)b2[lane];
            double acc[2][2] = {{bb, bb}, {bb, bb}};
            for (int cin = 0; cin < 16; cin++)
#pragma unroll
                for (int ky = 0; ky < 3; ky++)
#pragma unroll
                    for (int kx = 0; kx < 3; kx++) {
                        double wv = (double)w2[((lane * 16 + cin) * 3 + ky) * 3 + kx];
#pragma unroll
                        for (int sy = 0; sy < 2; sy++)
#pragma unroll
                            for (int sx = 0; sx < 2; sx++)
                                acc[sy][sx] += wv * h1w[cin][(sy + ky) * 4 + (sx + kx)];
                    }
            xvd[lane] = fmax(fmax(acc[0][0], acc[0][1]), fmax(acc[1][0], acc[1][1]));
        }
        __syncthreads();

        double x2 = 0.0;
        for (int d = 0; d < 32; d++) x2 += xvd[d] * xvd[d];
        double best = INFINITY;
        int bi = 0;
        for (int j = 0; j < 8; j++) {
            int k = lane * 8 + j;
            const float* cp = cb + k * 32;
            double c2 = 0.0, dot = 0.0;
#pragma unroll
            for (int d = 0; d < 32; d++) {
                double cd = (double)cp[d];
                c2 += cd * cd;
                dot += xvd[d] * cd;
            }
            double dist = x2 - 2.0 * dot + c2;
            if (dist < best) { best = dist; bi = k; }
        }
#pragma unroll
        for (int o = 32; o > 0; o >>= 1) {
            double od = __shfl_down(best, o);
            int oi = __shfl_down(bi, o);
            if (od < best || (od == best && oi < bi)) { best = od; bi = oi; }
        }
        bi = __shfl(bi, 0);

        if (lane == 0) idx_out[(size_t)n * 4096 + sp] = (float)bi;
    }
}

// prep: parity decoder weights + split-bf16 conv2 weights + split codebook.
__global__ __launch_bounds__(256) void k_prep(const float* __restrict__ w2,
                                              const float* __restrict__ w3,
                                              const float* __restrict__ w4,
                                              const float* __restrict__ cb,
                                              unsigned short* __restrict__ w2h,
                                              unsigned short* __restrict__ w2l,
                                              float* __restrict__ wc3,
                                              float* __restrict__ wc4,
                                              unsigned short* __restrict__ cbh,
                                              unsigned short* __restrict__ cbl,
                                              float* __restrict__ c2g) {
    const int masks[2][2] = {{1, 6}, {3, 4}};
    for (int e = threadIdx.x; e < 8192; e += 256) {
        int cout = e & 15, tap = (e >> 4) & 3, cin = (e >> 6) & 31, pp = e >> 11;
        int rm = masks[pp >> 1][tap >> 1], cm = masks[pp & 1][tap & 1];
        float s = 0.0f;
        for (int ky = 0; ky < 3; ky++)
            if ((rm >> ky) & 1)
                for (int kx = 0; kx < 3; kx++)
                    if ((cm >> kx) & 1) s += w3[(cout * 32 + cin) * 9 + ky * 3 + kx];
        wc3[e] = s;
    }
    for (int e = threadIdx.x; e < 1024; e += 256) {
        int tap = e & 3, cin = (e >> 2) & 15, pp = e >> 6;
        int rm = masks[pp >> 1][tap >> 1], cm = masks[pp & 1][tap & 1];
        float s = 0.0f;
        for (int ky = 0; ky < 3; ky++)
            if ((rm >> ky) & 1)
                for (int kx = 0; kx < 3; kx++)
                    if ((cm >> kx) & 1) s += w4[cin * 9 + ky * 3 + kx];
        wc4[e] = s;
    }
    for (int e = threadIdx.x; e < 5120; e += 256) {
        int cout = e / 160;
        int rem = e - cout * 160;
        int tap = rem >> 4;
        int cin = rem & 15;
        float v = 0.0f;
        if (tap < 9) {
            int ky = tap / 3, kx = tap - 3 * (tap / 3);
            v = w2[((cout * 16 + cin) * 3 + ky) * 3 + kx];
        }
        unsigned short hi = f2bf(v);
        unsigned short lo = f2bf(v - bf2f(hi));
        w2h[e] = hi;
        w2l[e] = lo;
    }
    for (int e = threadIdx.x; e < 16384; e += 256) {
        float v = cb[e];
        unsigned short hi = f2bf(v);
        cbh[e] = hi;
        cbl[e] = f2bf(v - bf2f(hi));
    }
    for (int k = threadIdx.x; k < 512; k += 256) {
        float c2 = 0.0f;
#pragma unroll
        for (int d = 0; d < 32; d++) {
            float fe = cb[k * 32 + d];
            c2 += fe * fe;
        }
        c2g[k] = c2;
    }
}

// Fused decoder: codes -> (LUT adds + gelu) h3 tile in LDS -> conv4 -> clip.
// Block = 16x16 h3 positions (128-grid); halo tile 18x18 x 16ch in LDS.
// h3 pixel (Y,X) needs codes ((Y>>1)-1+(Y&1)+dy, (X>>1)-1+(X&1)+dx), dy,dx in
// {0,1}; tap=dy*2+dx; pp=(Y&1)*2+(X&1). grid = 64 img * 64 tiles.
__global__ __launch_bounds__(256) void k_dec(const float* __restrict__ idxf,
                                             const float* __restrict__ lut,
                                             const float* __restrict__ b3,
                                             const float* __restrict__ wc4,
                                             const float* __restrict__ b4,
                                             float* __restrict__ out) {
    __shared__ int   s_code[11 * 11];
    __shared__ float s_h3[16 * 324];   // [ch][18*18]

    int tid = threadIdx.x;
    int n = blockIdx.x >> 6;
    int tile = blockIdx.x & 63;
    int ty = tile >> 3, tx = tile & 7;

    // stage 11x11 codes (base 8ty-1, 8tx-1); OOB -> 512 (LUT zero row)
    if (tid < 121) {
        int row = tid / 11, col = tid - row * 11;
        int ca = 8 * ty - 1 + row, cbx = 8 * tx - 1 + col;
        int code = 512;
        if (ca >= 0 && ca < 64 && cbx >= 0 && cbx < 64)
            code = (int)idxf[((size_t)n << 12) + (ca << 6) + cbx];
        s_code[tid] = code;
    }
    __syncthreads();

    // h3 halo tile: 324 positions x 16 ch
    for (int e = tid; e < 324; e += 256) {
        int r = e / 18, cc = e - r * 18;
        int Y = 16 * ty - 1 + r, X = 16 * tx - 1 + cc;
        float hv[16];
        if (Y >= 0 && Y < 128 && X >= 0 && X < 128) {
            int pp = ((Y & 1) << 1) | (X & 1);
            int la0 = (Y >> 1) - 1 + (Y & 1) - (8 * ty - 1);
            int lb0 = (X >> 1) - 1 + (X & 1) - (8 * tx - 1);
            float acc[16];
#pragma unroll
            for (int c = 0; c < 16; c++) acc[c] = b3[c];
#pragma unroll
            for (int dy = 0; dy < 2; dy++)
#pragma unroll
                for (int dx = 0; dx < 2; dx++) {
                    int code = s_code[(la0 + dy) * 11 + lb0 + dx];
                    const float4* lp = (const float4*)(lut + (size_t)code * 256 +
                                                       pp * 64 + (dy * 2 + dx) * 16);
#pragma unroll
                    for (int j = 0; j < 4; j++) {
                        float4 w = lp[j];
                        acc[4 * j + 0] += w.x;
                        acc[4 * j + 1] += w.y;
                        acc[4 * j + 2] += w.z;
                        acc[4 * j + 3] += w.w;
                    }
                }
#pragma unroll
            for (int c = 0; c < 16; c++) hv[c] = GELUF(acc[c]);
        } else {
#pragma unroll
            for (int c = 0; c < 16; c++) hv[c] = 0.0f;  // conv4 SAME zero-pad
        }
#pragma unroll
        for (int c = 0; c < 16; c++) s_h3[c * 324 + e] = hv[c];
    }
    __syncthreads();

    // conv4 from LDS tile: thread -> 128-grid pos (a,b); 2x2 outputs
    int ly = tid >> 4, lx = tid & 15;
    float bv = b4[0];
    float acc2[2][2] = {{bv, bv}, {bv, bv}};
    for (int cin = 0; cin < 16; cin++) {
        const float* hc = s_h3 + cin * 324;
        float v[3][3];
#pragma unroll
        for (int r = 0; r < 3; r++)
#pragma unroll
            for (int cc = 0; cc < 3; cc++)
                v[r][cc] = hc[(ly + r) * 18 + lx + cc];
#pragma unroll
        for (int py = 0; py < 2; py++)
#pragma unroll
            for (int px = 0; px < 2; px++)
#pragma unroll
                for (int dy = 0; dy < 2; dy++)
#pragma unroll
                    for (int dx = 0; dx < 2; dx++)
                        acc2[py][px] += wc4[(py * 2 + px) * 64 + cin * 4 + dy * 2 + dx] *
                                        v[py + dy][px + dx];
    }
    int a = 16 * ty + ly, b = 16 * tx + lx;
#pragma unroll
    for (int py = 0; py < 2; py++) {
        float2 f2 = make_float2(fminf(fmaxf(acc2[py][0], -1.0f), 1.0f),
                                fminf(fmaxf(acc2[py][1], -1.0f), 1.0f));
        *(float2*)(out + (size_t)n * 65536 + (2 * a + py) * 256 + 2 * b) = f2;
    }
}

extern "C" void kernel_launch(void* const* d_in, const int* in_sizes, int n_in,
                              void* d_out, int out_size, void* d_ws, size_t ws_size,
                              hipStream_t stream) {
    const float* x  = (const float*)d_in[0];
    const float* w1 = (const float*)d_in[1];
    const float* b1 = (const float*)d_in[2];
    const float* w2 = (const float*)d_in[3];
    const float* b2 = (const float*)d_in[4];
    const float* cb = (const float*)d_in[5];
    const float* w3 = (const float*)d_in[6];
    const float* b3 = (const float*)d_in[7];
    const float* w4 = (const float*)d_in[8];
    const float* b4 = (const float*)d_in[9];

    float* out      = (float*)d_out;
    float* idx_out  = out + 4194304;
    float* loss_out = out + 4194304 + 262144;

    char* ws = (char*)d_ws;
    unsigned short* h1h = (unsigned short*)ws;                      // [0,32M)
    unsigned short* h1l = (unsigned short*)(ws + (size_t)33554432); // [32M,64M)
    float* h2  = (float*)(ws + (size_t)67108864);                   // [64M,96M)
    float* lut = (float*)(ws + (size_t)67108864);                   // over dead h2
    size_t T = 100663296;
    float* wc3 = (float*)(ws + T);                             // 32 KB
    float* wc4 = (float*)(ws + T + 32768);                     // 4 KB
    unsigned short* w2h = (unsigned short*)(ws + T + 36864);   // 10240 B
    unsigned short* w2l = (unsigned short*)(ws + T + 47104);   // 10240 B
    int* nflag = (int*)(ws + T + 57344);
    int* flags = (int*)(ws + T + 57408);                       // 1 MB
    size_t T2 = T + 57408 + 1048576;
    unsigned short* cbh = (unsigned short*)(ws + T2);          // 32 KB
    unsigned short* cbl = (unsigned short*)(ws + T2 + 32768);  // 32 KB
    float* c2g = (float*)(ws + T2 + 65536);                    // 2 KB

    (void)hipMemsetAsync(loss_out, 0, 4, stream);
    (void)hipMemsetAsync(nflag, 0, 4, stream);

    k_prep<<<1, 256, 0, stream>>>(w2, w3, w4, cb, w2h, w2l, wc3, wc4, cbh, cbl, c2g);
    k_conv1b<<<4096, 256, 0, stream>>>(x, w1, b1, h1h, h1l);
    k_conv2m<<<4096, 256, 0, stream>>>(h1h, h1l, w2h, w2l, b2, h2);
    k_vq_mfma<<<2048, 128, 0, stream>>>(h2, cbh, cbl, c2g, idx_out, loss_out, nflag, flags);
    k_lut<<<513, 256, 0, stream>>>(wc3, cb, lut);   // into dead h2 region (after vq)
    k_repair<<<16384, 64, 0, stream>>>(x, w1, b1, w2, b2, cb, idx_out, nflag, flags);
    k_dec<<<4096, 256, 0, stream>>>(idx_out, lut, b3, wc4, b4, out);
}

// Round 12
// 403.010 us; speedup vs baseline: 1.1883x; 1.0190x over previous
//
#include <hip/hip_runtime.h>
#include <math.h>

// ---------------------------------------------------------------------------
// SimpleVQAutoEncoder forward.
// conv1 (LDS-tiled) -> h1 split-bf16 hi/lo [n][y][x][cin]; conv2 split-bf16
// MFMA GEMM. VQ: split-bf16 MFMA distances (codebook pre-split, L2-direct
// B-frags, 256-thr blocks); near-tie flagging + fp64 repair => indices ==
// numpy fp64. q never materialized: decoder uses LUT[code][pp][tap][cout].
// Decoder: single fused kernel k_dec (LUT adds -> gelu tile in LDS -> conv4).
// Outputs d_out (fp32): recon 4194304 | indices 262144 | loss 1
// ---------------------------------------------------------------------------

#define GELUF(v) (0.5f * (v) * (1.0f + erff((v) * 0.70710678118654752440f)))
#define MAXFLAG 262144

typedef __attribute__((ext_vector_type(8))) short short8;
typedef __attribute__((ext_vector_type(4))) float float4v;

static __device__ inline unsigned short f2bf(float f) {
    unsigned u = __float_as_uint(f);
    unsigned r = (u + 0x7FFFu + ((u >> 16) & 1u)) >> 16;
    return (unsigned short)r;
}
static __device__ inline float bf2f(unsigned short h) {
    return __uint_as_float(((unsigned)h) << 16);
}

// conv1 (1->16) + maxpool2 + gelu, LDS-tiled. Block = 16x16 pooled tile; LDS
// holds the 34x34 input window (stride 36). Output split-bf16 [n][y][x][cin].
__global__ __launch_bounds__(256) void k_conv1t(const float* __restrict__ x,
                                                const float* __restrict__ w1,
                                                const float* __restrict__ b1,
                                                unsigned short* __restrict__ h1h,
                                                unsigned short* __restrict__ h1l) {
    __shared__ float s_x[34 * 36];  // 4.9 KB

    int tid = threadIdx.x;
    int n = blockIdx.x >> 6;
    int tile = blockIdx.x & 63;
    int ty = tile >> 3, tx = tile & 7;
    const float* xin = x + (size_t)n * 65536;

    int gy0 = 32 * ty - 1, gx0 = 32 * tx - 1;
    for (int e = tid; e < 1156; e += 256) {
        int r = e / 34, c = e - r * 34;
        int gy = gy0 + r, gx = gx0 + c;
        float v = 0.0f;
        if (gy >= 0 && gy < 256 && gx >= 0 && gx < 256)
            v = xin[gy * 256 + gx];
        s_x[r * 36 + c] = v;
    }
    __syncthreads();

    int ly = tid >> 4, lx = tid & 15;
    float patch[4][4];
    const float* sp = s_x + (2 * ly) * 36 + 2 * lx;
#pragma unroll
    for (int i = 0; i < 4; i++)
#pragma unroll
        for (int j = 0; j < 4; j++)
            patch[i][j] = sp[i * 36 + j];

    unsigned short hi[16], lo[16];
#pragma unroll
    for (int c = 0; c < 16; c++) {
        float m = -INFINITY;
#pragma unroll
        for (int sy = 0; sy < 2; sy++)
#pragma unroll
            for (int sx = 0; sx < 2; sx++) {
                float acc = b1[c];
#pragma unroll
                for (int ky = 0; ky < 3; ky++)
#pragma unroll
                    for (int kx = 0; kx < 3; kx++)
                        acc += w1[c * 9 + ky * 3 + kx] * patch[sy + ky][sx + kx];
                m = fmaxf(m, acc);
            }
        float g = GELUF(m);
        hi[c] = f2bf(g);
        lo[c] = f2bf(g - bf2f(hi[c]));
    }

    int yo = 16 * ty + ly, xo = 16 * tx + lx;
    size_t off = ((size_t)((n << 14) + (yo << 7) + xo)) << 4;
    uint ph[8], pl[8];
#pragma unroll
    for (int c2 = 0; c2 < 8; c2++) {
        ph[c2] = (uint)hi[2 * c2] | ((uint)hi[2 * c2 + 1] << 16);
        pl[c2] = (uint)lo[2 * c2] | ((uint)lo[2 * c2 + 1] << 16);
    }
    uint4* dh = (uint4*)(h1h + off);
    uint4* dl = (uint4*)(h1l + off);
    dh[0] = make_uint4(ph[0], ph[1], ph[2], ph[3]);
    dh[1] = make_uint4(ph[4], ph[5], ph[6], ph[7]);
    dl[0] = make_uint4(pl[0], pl[1], pl[2], pl[3]);
    dl[1] = make_uint4(pl[4], pl[5], pl[6], pl[7]);
}

// conv2 (16->32) + maxpool2 via split-bf16 MFMA (unchanged).
__global__ __launch_bounds__(256) void k_conv2m(const unsigned short* __restrict__ h1h,
                                                const unsigned short* __restrict__ h1l,
                                                const unsigned short* __restrict__ w2h,
                                                const unsigned short* __restrict__ w2l,
                                                const float* __restrict__ b2,
                                                float* __restrict__ h2) {
    __shared__ unsigned short s_hi[18 * 2 * 18 * 8];
    __shared__ unsigned short s_lo[18 * 2 * 18 * 8];
    __shared__ unsigned short s_wh[32 * 10 * 2 * 8];
    __shared__ unsigned short s_wl[32 * 10 * 2 * 8];
    __shared__ float s_pool[32 * 64];

    int tid = threadIdx.x;
    int n = blockIdx.x >> 6;
    int tile = blockIdx.x & 63;
    int cx0 = (tile & 7) << 4, cy0 = (tile >> 3) << 4;

    {
        const uint* gh = (const uint*)w2h;
        const uint* gl = (const uint*)w2l;
        uint* dh = (uint*)s_wh; uint* dl = (uint*)s_wl;
        for (int e = tid; e < 2560; e += 256) { dh[e] = gh[e]; dl[e] = gl[e]; }
    }
    {
        const uint* gh = (const uint*)(h1h + (((size_t)n) << 18));
        const uint* gl = (const uint*)(h1l + (((size_t)n) << 18));
        uint* dh = (uint*)s_hi; uint* dl = (uint*)s_lo;
        for (int e = tid; e < 2592; e += 256) {
            int r = e / 144;
            int rem = e - r * 144;
            int c = rem >> 3;
            int dw = rem & 7;
            int y = cy0 - 1 + r, xx = cx0 - 1 + c;
            uint vh = 0, vl = 0;
            if (y >= 0 && y < 128 && xx >= 0 && xx < 128) {
                size_t g = ((size_t)((y << 7) + xx) << 3) + dw;
                vh = gh[g]; vl = gl[g];
            }
            int half = dw >> 2;
            int du = (((r * 2 + half) * 18 + c) << 2) + (dw & 3);
            dh[du] = vh; dl[du] = vl;
        }
    }
    __syncthreads();

    int lane = tid & 63, wid = tid >> 6;
    int m = lane & 15, quad = lane >> 4;
    int tl = quad >> 1, half = quad & 1;

    float4v acc[4][2];
#pragma unroll
    for (int mt = 0; mt < 4; mt++)
#pragma unroll
        for (int nt = 0; nt < 2; nt++)
            acc[mt][nt] = (float4v){0.0f, 0.0f, 0.0f, 0.0f};

    for (int s = 0; s < 5; s++) {
        int tA = (s < 4) ? (2 * s + tl) : 8;
        int tB = (s < 4) ? (2 * s + tl) : (8 + tl);
        short8 Bh[2], Bl[2];
#pragma unroll
        for (int nt = 0; nt < 2; nt++) {
            int u = ((nt * 16 + m) * 10 + tB) * 2 + half;
            Bh[nt] = *(const short8*)(s_wh + (u << 3));
            Bl[nt] = *(const short8*)(s_wl + (u << 3));
        }
        int ky = tA / 3, kx = tA - 3 * (tA / 3);
        short8 Ah[4], Al[4];
#pragma unroll
        for (int mt = 0; mt < 4; mt++) {
            int u = (((wid * 4 + mt + ky) * 2 + half) * 18) + m + kx;
            Ah[mt] = *(const short8*)(s_hi + (u << 3));
            Al[mt] = *(const short8*)(s_lo + (u << 3));
        }
#pragma unroll
        for (int mt = 0; mt < 4; mt++)
#pragma unroll
            for (int nt = 0; nt < 2; nt++) {
                float4v z = acc[mt][nt];
                z = __builtin_amdgcn_mfma_f32_16x16x32_bf16(Al[mt], Bh[nt], z, 0, 0, 0);
                z = __builtin_amdgcn_mfma_f32_16x16x32_bf16(Ah[mt], Bl[nt], z, 0, 0, 0);
                z = __builtin_amdgcn_mfma_f32_16x16x32_bf16(Ah[mt], Bh[nt], z, 0, 0, 0);
                acc[mt][nt] = z;
            }
    }

#pragma unroll
    for (int nt = 0; nt < 2; nt++) {
        int cout = nt * 16 + m;
        float bias = b2[cout];
#pragma unroll
        for (int mtp = 0; mtp < 2; mtp++) {
            float4v a0 = acc[2 * mtp][nt], a1 = acc[2 * mtp + 1][nt];
            float p0 = fmaxf(fmaxf(a0[0], a0[1]), fmaxf(a1[0], a1[1])) + bias;
            float p1 = fmaxf(fmaxf(a0[2], a0[3]), fmaxf(a1[2], a1[3])) + bias;
            int py = wid * 2 + mtp;
            int px = quad * 2;
            s_pool[cout * 64 + py * 8 + px]     = p0;
            s_pool[cout * 64 + py * 8 + px + 1] = p1;
        }
    }
    __syncthreads();
    {
        int c = tid >> 3, pr = tid & 7;
        float* dst = h2 + (((size_t)(n * 32 + c)) << 12) + ((cy0 >> 1) + pr) * 64 + (cx0 >> 1);
        const float4* src = (const float4*)(s_pool + c * 64 + pr * 8);
        ((float4*)dst)[0] = src[0];
        ((float4*)dst)[1] = src[1];
    }
}

// VQ via split-bf16 MFMA — R10 config restored (256 threads, 1024 blocks).
__global__ __launch_bounds__(256) void k_vq_mfma(const float* __restrict__ h2,
                                                 const unsigned short* __restrict__ cbh,
                                                 const unsigned short* __restrict__ cbl,
                                                 const float* __restrict__ c2g,
                                                 float* __restrict__ idx_out,
                                                 float* __restrict__ loss_out,
                                                 int* __restrict__ nflag,
                                                 int* __restrict__ flags) {
    __shared__ float s_best[256], s_best2[256];
    __shared__ int   s_bi[256];
    __shared__ float wsum[4];

    int tid = threadIdx.x;
    int lane = tid & 63;
    int wid  = tid >> 6;
    int m    = lane & 15;
    int quad = lane >> 4;

    int img = blockIdx.x >> 4;
    int sp0 = (blockIdx.x & 15) << 8;
    const float* xb = h2 + ((size_t)(img * 32) << 12) + sp0;

    short8 Ahi[4], Alo[4];
    float x2r[4][4];
    float x2own[4];
#pragma unroll
    for (int mt = 0; mt < 4; mt++) {
        const float* xp = xb + wid * 64 + mt * 16 + m;
        float x2 = 0.0f;
#pragma unroll
        for (int j = 0; j < 8; j++) {
            float fe = xp[(size_t)(quad * 8 + j) << 12];
            x2 += fe * fe;
            unsigned short hi = f2bf(fe);
            unsigned short lo = f2bf(fe - bf2f(hi));
            Ahi[mt][j] = (short)hi;
            Alo[mt][j] = (short)lo;
        }
        x2 += __shfl_xor(x2, 16);
        x2 += __shfl_xor(x2, 32);
        x2own[mt] = x2;
    }
#pragma unroll
    for (int mt = 0; mt < 4; mt++)
#pragma unroll
        for (int r = 0; r < 4; r++)
            x2r[mt][r] = __shfl(x2own[mt], quad * 4 + r);

    float best[4][4], best2[4][4];
    int bi[4][4];
#pragma unroll
    for (int mt = 0; mt < 4; mt++)
#pragma unroll
        for (int r = 0; r < 4; r++) {
            best[mt][r] = INFINITY; best2[mt][r] = INFINITY; bi[mt][r] = 0;
        }

    size_t boff = ((size_t)m << 5) + (quad << 3);
    short8 Bh = *(const short8*)(cbh + boff);
    short8 Bl = *(const short8*)(cbl + boff);
    float  c2v = c2g[m];

    for (int nt = 0; nt < 32; nt++) {
        short8 curBh = Bh, curBl = Bl;
        float  curc2 = c2v;
        if (nt < 31) {
            size_t o = boff + ((size_t)(nt + 1) << 9);
            Bh = *(const short8*)(cbh + o);
            Bl = *(const short8*)(cbl + o);
            c2v = c2g[(nt + 1) * 16 + m];
        }
        int ncode = nt * 16 + m;

        float4v acc[4];
#pragma unroll
        for (int mt = 0; mt < 4; mt++) {
            float4v z = {0.0f, 0.0f, 0.0f, 0.0f};
            z = __builtin_amdgcn_mfma_f32_16x16x32_bf16(Alo[mt], curBh, z, 0, 0, 0);
            z = __builtin_amdgcn_mfma_f32_16x16x32_bf16(Ahi[mt], curBl, z, 0, 0, 0);
            z = __builtin_amdgcn_mfma_f32_16x16x32_bf16(Ahi[mt], curBh, z, 0, 0, 0);
            acc[mt] = z;
        }
#pragma unroll
        for (int mt = 0; mt < 4; mt++)
#pragma unroll
            for (int r = 0; r < 4; r++) {
                float dist = fmaf(acc[mt][r], -2.0f, curc2);
                best2[mt][r] = fminf(best2[mt][r], fmaxf(dist, best[mt][r]));
                bool lt = dist < best[mt][r];
                bi[mt][r] = lt ? ncode : bi[mt][r];
                best[mt][r] = fminf(best[mt][r], dist);
            }
    }

#pragma unroll
    for (int mt = 0; mt < 4; mt++)
#pragma unroll
        for (int r = 0; r < 4; r++) {
            float b1v = best[mt][r], b2v = best2[mt][r];
            int   biv = bi[mt][r];
#pragma unroll
            for (int mask = 1; mask < 16; mask <<= 1) {
                float ob = __shfl_xor(b1v, mask);
                float ob2 = __shfl_xor(b2v, mask);
                int   obi = __shfl_xor(biv, mask);
                b2v = fminf(fminf(b2v, ob2), fmaxf(b1v, ob));
                if (ob < b1v || (ob == b1v && obi < biv)) { b1v = ob; biv = obi; }
            }
            if (m == 0) {
                int p = wid * 64 + mt * 16 + quad * 4 + r;
                s_best[p] = b1v + x2r[mt][r];
                s_best2[p] = b2v + x2r[mt][r];
                s_bi[p] = biv;
            }
        }
    __syncthreads();

    int pos = blockIdx.x * 256 + tid;
    float bb = s_best[tid], bb2 = s_best2[tid];
    int   kk = s_bi[tid];
    idx_out[pos] = (float)kk;

    float eps = 0.02f + 0.0005f * fabsf(bb);
    if (bb2 - bb < eps) {
        int slot = atomicAdd(nflag, 1);
        if (slot < MAXFLAG) flags[slot] = pos;
    }

    float lsum = fmaxf(bb, 0.0f);
#pragma unroll
    for (int o = 32; o > 0; o >>= 1) lsum += __shfl_down(lsum, o);
    if (lane == 0) wsum[wid] = lsum;
    __syncthreads();
    if (tid == 0)
        atomicAdd(loss_out, (wsum[0] + wsum[1] + wsum[2] + wsum[3]) * (1.0f / 8388608.0f));
}

// LUT[code][pp][tap][cout] = sum_cin wc3[pp][cin][tap][cout] * cb[code][cin].
__global__ __launch_bounds__(256) void k_lut(const float* __restrict__ wc3,
                                             const float* __restrict__ cb,
                                             float* __restrict__ lut) {
    int code = blockIdx.x;
    int t = threadIdx.x;
    float s = 0.0f;
    if (code < 512) {
        int pp = t >> 6, rem = t & 63;
        const float* wp = wc3 + pp * 2048 + rem;
        const float* cr = cb + code * 32;
        for (int cin = 0; cin < 32; cin++)
            s += wp[cin * 64] * cr[cin];
    }
    lut[(size_t)code * 256 + t] = s;
}

// fp64 repair: fixes idx_out only (unchanged).
__global__ __launch_bounds__(64) void k_repair(const float* __restrict__ x,
                                               const float* __restrict__ w1,
                                               const float* __restrict__ b1,
                                               const float* __restrict__ w2,
                                               const float* __restrict__ b2,
                                               const float* __restrict__ cb,
                                               float* __restrict__ idx_out,
                                               const int* __restrict__ nflag,
                                               const int* __restrict__ flags) {
    __shared__ double h1w[16][16];
    __shared__ double xvd[32];
    int lane = threadIdx.x;
    int cnt = *nflag;
    if (cnt > MAXFLAG) cnt = MAXFLAG;

    for (int fi = blockIdx.x; fi < cnt; fi += gridDim.x) {
        int pos = flags[fi];
        int n = pos >> 12, sp = pos & 4095, yo = sp >> 6, xo = sp & 63;

        int pix = lane >> 2, cg = lane & 3;
        int dy = pix >> 2, dx = pix & 3;
        int yh = 2 * yo - 1 + dy, xh = 2 * xo - 1 + dx;
        double hv[4] = {0.0, 0.0, 0.0, 0.0};
        if (yh >= 0 && yh < 128 && xh >= 0 && xh < 128) {
            const float* xin = x + (size_t)n * 65536;
            double patch[4][4];
            int y0 = 2 * yh - 1, x0 = 2 * xh - 1;
#pragma unroll
            for (int i = 0; i < 4; i++) {
                int iy = y0 + i;
                bool oy = (iy >= 0 && iy < 256);
#pragma unroll
                for (int j = 0; j < 4; j++) {
                    int ix = x0 + j;
                    patch[i][j] = (oy && ix >= 0 && ix < 256) ? (double)xin[iy * 256 + ix] : 0.0;
                }
            }
#pragma unroll
            for (int j = 0; j < 4; j++) {
                int c = cg * 4 + j;
                double mm = -INFINITY;
#pragma unroll
                for (int sy = 0; sy < 2; sy++)
#pragma unroll
                    for (int sx = 0; sx < 2; sx++) {
                        double acc = (double)b1[c];
#pragma unroll
                        for (int ky = 0; ky < 3; ky++)
#pragma unroll
                            for (int kx = 0; kx < 3; kx++)
                                acc += (double)w1[c * 9 + ky * 3 + kx] * patch[sy + ky][sx + kx];
                        mm = fmax(mm, acc);
                    }
                hv[j] = 0.5 * mm * (1.0 + erf(mm * 0.70710678118654752440));
            }
        }
        __syncthreads();
#pragma unroll
        for (int j = 0; j < 4; j++) h1w[cg * 4 + j][pix] = hv[j];
        __syncthreads();

        if (lane < 32) {
            double bb = (double)b2[lane];
            double acc[2][2] = {{bb, bb}, {bb, bb}};
            for (int cin = 0; cin < 16; cin++)
#pragma unroll
                for (int ky = 0; ky < 3; ky++)
#pragma unroll
                    for (int kx = 0; kx < 3; kx++) {
                        double wv = (double)w2[((lane * 16 + cin) * 3 + ky) * 3 + kx];
#pragma unroll
                        for (int sy = 0; sy < 2; sy++)
#pragma unroll
                            for (int sx = 0; sx < 2; sx++)
                                acc[sy][sx] += wv * h1w[cin][(sy + ky) * 4 + (sx + kx)];
                    }
            xvd[lane] = fmax(fmax(acc[0][0], acc[0][1]), fmax(acc[1][0], acc[1][1]));
        }
        __syncthreads();

        double x2 = 0.0;
        for (int d = 0; d < 32; d++) x2 += xvd[d] * xvd[d];
        double best = INFINITY;
        int bi = 0;
        for (int j = 0; j < 8; j++) {
            int k = lane * 8 + j;
            const float* cp = cb + k * 32;
            double c2 = 0.0, dot = 0.0;
#pragma unroll
            for (int d = 0; d < 32; d++) {
                double cd = (double)cp[d];
                c2 += cd * cd;
                dot += xvd[d] * cd;
            }
            double dist = x2 - 2.0 * dot + c2;
            if (dist < best) { best = dist; bi = k; }
        }
#pragma unroll
        for (int o = 32; o > 0; o >>= 1) {
            double od = __shfl_down(best, o);
            int oi = __shfl_down(bi, o);
            if (od < best || (od == best && oi < bi)) { best = od; bi = oi; }
        }
        bi = __shfl(bi, 0);

        if (lane == 0) idx_out[(size_t)n * 4096 + sp] = (float)bi;
    }
}

// prep: parity decoder weights + split-bf16 conv2 weights + split codebook.
__global__ __launch_bounds__(256) void k_prep(const float* __restrict__ w2,
                                              const float* __restrict__ w3,
                                              const float* __restrict__ w4,
                                              const float* __restrict__ cb,
                                              unsigned short* __restrict__ w2h,
                                              unsigned short* __restrict__ w2l,
                                              float* __restrict__ wc3,
                                              float* __restrict__ wc4,
                                              unsigned short* __restrict__ cbh,
                                              unsigned short* __restrict__ cbl,
                                              float* __restrict__ c2g) {
    const int masks[2][2] = {{1, 6}, {3, 4}};
    for (int e = threadIdx.x; e < 8192; e += 256) {
        int cout = e & 15, tap = (e >> 4) & 3, cin = (e >> 6) & 31, pp = e >> 11;
        int rm = masks[pp >> 1][tap >> 1], cm = masks[pp & 1][tap & 1];
        float s = 0.0f;
        for (int ky = 0; ky < 3; ky++)
            if ((rm >> ky) & 1)
                for (int kx = 0; kx < 3; kx++)
                    if ((cm >> kx) & 1) s += w3[(cout * 32 + cin) * 9 + ky * 3 + kx];
        wc3[e] = s;
    }
    for (int e = threadIdx.x; e < 1024; e += 256) {
        int tap = e & 3, cin = (e >> 2) & 15, pp = e >> 6;
        int rm = masks[pp >> 1][tap >> 1], cm = masks[pp & 1][tap & 1];
        float s = 0.0f;
        for (int ky = 0; ky < 3; ky++)
            if ((rm >> ky) & 1)
                for (int kx = 0; kx < 3; kx++)
                    if ((cm >> kx) & 1) s += w4[cin * 9 + ky * 3 + kx];
        wc4[e] = s;
    }
    for (int e = threadIdx.x; e < 5120; e += 256) {
        int cout = e / 160;
        int rem = e - cout * 160;
        int tap = rem >> 4;
        int cin = rem & 15;
        float v = 0.0f;
        if (tap < 9) {
            int ky = tap / 3, kx = tap - 3 * (tap / 3);
            v = w2[((cout * 16 + cin) * 3 + ky) * 3 + kx];
        }
        unsigned short hi = f2bf(v);
        unsigned short lo = f2bf(v - bf2f(hi));
        w2h[e] = hi;
        w2l[e] = lo;
    }
    for (int e = threadIdx.x; e < 16384; e += 256) {
        float v = cb[e];
        unsigned short hi = f2bf(v);
        cbh[e] = hi;
        cbl[e] = f2bf(v - bf2f(hi));
    }
    for (int k = threadIdx.x; k < 512; k += 256) {
        float c2 = 0.0f;
#pragma unroll
        for (int d = 0; d < 32; d++) {
            float fe = cb[k * 32 + d];
            c2 += fe * fe;
        }
        c2g[k] = c2;
    }
}

// Fused decoder (unchanged from R11): codes -> LUT adds + gelu -> conv4.
__global__ __launch_bounds__(256) void k_dec(const float* __restrict__ idxf,
                                             const float* __restrict__ lut,
                                             const float* __restrict__ b3,
                                             const float* __restrict__ wc4,
                                             const float* __restrict__ b4,
                                             float* __restrict__ out) {
    __shared__ int   s_code[11 * 11];
    __shared__ float s_h3[16 * 324];

    int tid = threadIdx.x;
    int n = blockIdx.x >> 6;
    int tile = blockIdx.x & 63;
    int ty = tile >> 3, tx = tile & 7;

    if (tid < 121) {
        int row = tid / 11, col = tid - row * 11;
        int ca = 8 * ty - 1 + row, cbx = 8 * tx - 1 + col;
        int code = 512;
        if (ca >= 0 && ca < 64 && cbx >= 0 && cbx < 64)
            code = (int)idxf[((size_t)n << 12) + (ca << 6) + cbx];
        s_code[tid] = code;
    }
    __syncthreads();

    for (int e = tid; e < 324; e += 256) {
        int r = e / 18, cc = e - r * 18;
        int Y = 16 * ty - 1 + r, X = 16 * tx - 1 + cc;
        float hv[16];
        if (Y >= 0 && Y < 128 && X >= 0 && X < 128) {
            int pp = ((Y & 1) << 1) | (X & 1);
            int la0 = (Y >> 1) - 1 + (Y & 1) - (8 * ty - 1);
            int lb0 = (X >> 1) - 1 + (X & 1) - (8 * tx - 1);
            float acc[16];
#pragma unroll
            for (int c = 0; c < 16; c++) acc[c] = b3[c];
#pragma unroll
            for (int dy = 0; dy < 2; dy++)
#pragma unroll
                for (int dx = 0; dx < 2; dx++) {
                    int code = s_code[(la0 + dy) * 11 + lb0 + dx];
                    const float4* lp = (const float4*)(lut + (size_t)code * 256 +
                                                       pp * 64 + (dy * 2 + dx) * 16);
#pragma unroll
                    for (int j = 0; j < 4; j++) {
                        float4 w = lp[j];
                        acc[4 * j + 0] += w.x;
                        acc[4 * j + 1] += w.y;
                        acc[4 * j + 2] += w.z;
                        acc[4 * j + 3] += w.w;
                    }
                }
#pragma unroll
            for (int c = 0; c < 16; c++) hv[c] = GELUF(acc[c]);
        } else {
#pragma unroll
            for (int c = 0; c < 16; c++) hv[c] = 0.0f;
        }
#pragma unroll
        for (int c = 0; c < 16; c++) s_h3[c * 324 + e] = hv[c];
    }
    __syncthreads();

    int ly = tid >> 4, lx = tid & 15;
    float bv = b4[0];
    float acc2[2][2] = {{bv, bv}, {bv, bv}};
    for (int cin = 0; cin < 16; cin++) {
        const float* hc = s_h3 + cin * 324;
        float v[3][3];
#pragma unroll
        for (int r = 0; r < 3; r++)
#pragma unroll
            for (int cc = 0; cc < 3; cc++)
                v[r][cc] = hc[(ly + r) * 18 + lx + cc];
#pragma unroll
        for (int py = 0; py < 2; py++)
#pragma unroll
            for (int px = 0; px < 2; px++)
#pragma unroll
                for (int dy = 0; dy < 2; dy++)
#pragma unroll
                    for (int dx = 0; dx < 2; dx++)
                        acc2[py][px] += wc4[(py * 2 + px) * 64 + cin * 4 + dy * 2 + dx] *
                                        v[py + dy][px + dx];
    }
    int a = 16 * ty + ly, b = 16 * tx + lx;
#pragma unroll
    for (int py = 0; py < 2; py++) {
        float2 f2 = make_float2(fminf(fmaxf(acc2[py][0], -1.0f), 1.0f),
                                fminf(fmaxf(acc2[py][1], -1.0f), 1.0f));
        *(float2*)(out + (size_t)n * 65536 + (2 * a + py) * 256 + 2 * b) = f2;
    }
}

extern "C" void kernel_launch(void* const* d_in, const int* in_sizes, int n_in,
                              void* d_out, int out_size, void* d_ws, size_t ws_size,
                              hipStream_t stream) {
    const float* x  = (const float*)d_in[0];
    const float* w1 = (const float*)d_in[1];
    const float* b1 = (const float*)d_in[2];
    const float* w2 = (const float*)d_in[3];
    const float* b2 = (const float*)d_in[4];
    const float* cb = (const float*)d_in[5];
    const float* w3 = (const float*)d_in[6];
    const float* b3 = (const float*)d_in[7];
    const float* w4 = (const float*)d_in[8];
    const float* b4 = (const float*)d_in[9];

    float* out      = (float*)d_out;
    float* idx_out  = out + 4194304;
    float* loss_out = out + 4194304 + 262144;

    char* ws = (char*)d_ws;
    unsigned short* h1h = (unsigned short*)ws;                      // [0,32M)
    unsigned short* h1l = (unsigned short*)(ws + (size_t)33554432); // [32M,64M)
    float* h2  = (float*)(ws + (size_t)67108864);                   // [64M,96M)
    float* lut = (float*)(ws + (size_t)67108864);                   // over dead h2
    size_t T = 100663296;
    float* wc3 = (float*)(ws + T);
    float* wc4 = (float*)(ws + T + 32768);
    unsigned short* w2h = (unsigned short*)(ws + T + 36864);
    unsigned short* w2l = (unsigned short*)(ws + T + 47104);
    int* nflag = (int*)(ws + T + 57344);
    int* flags = (int*)(ws + T + 57408);                       // 1 MB
    size_t T2 = T + 57408 + 1048576;
    unsigned short* cbh = (unsigned short*)(ws + T2);
    unsigned short* cbl = (unsigned short*)(ws + T2 + 32768);
    float* c2g = (float*)(ws + T2 + 65536);

    (void)hipMemsetAsync(loss_out, 0, 4, stream);
    (void)hipMemsetAsync(nflag, 0, 4, stream);

    k_prep<<<1, 256, 0, stream>>>(w2, w3, w4, cb, w2h, w2l, wc3, wc4, cbh, cbl, c2g);
    k_conv1t<<<4096, 256, 0, stream>>>(x, w1, b1, h1h, h1l);
    k_conv2m<<<4096, 256, 0, stream>>>(h1h, h1l, w2h, w2l, b2, h2);
    k_vq_mfma<<<1024, 256, 0, stream>>>(h2, cbh, cbl, c2g, idx_out, loss_out, nflag, flags);
    k_lut<<<513, 256, 0, stream>>>(wc3, cb, lut);
    k_repair<<<16384, 64, 0, stream>>>(x, w1, b1, w2, b2, cb, idx_out, nflag, flags);
    k_dec<<<4096, 256, 0, stream>>>(idx_out, lut, b3, wc4, b4, out);
}